// Round 2
// baseline (23866.379 us; speedup 1.0000x reference)
//
#include <hip/hip_runtime.h>
#include <math.h>

// ---------------------------------------------------------------------------
// Problem constants (PatchTST-style transformer)
// ---------------------------------------------------------------------------
namespace {
constexpr int kB = 32, kT = 512, kC = 32, kD = 512, kH = 8, kDFF = 2048, kNL = 3;
constexpr int kP = 16, kStride = 8, kN = 64;
constexpr int kR = kB * kC;      // 1024 independent (b,c) series
constexpr int kM = kR * kN;      // 65536 tokens total
constexpr int kCH = 128;         // series per chunk
constexpr int kNCH = kR / kCH;   // 8 chunks
constexpr size_t kChunkRows = (size_t)kCH * kN;   // 8192
}

// bf16 <-> fp32 helpers (raw ushort storage, RNE rounding)
__device__ __forceinline__ float b2f(unsigned short u) {
    return __uint_as_float(((unsigned int)u) << 16);
}
__device__ __forceinline__ unsigned short f2b(float f) {
    unsigned int x = __float_as_uint(f);
    return (unsigned short)((x + 0x7fffu + ((x >> 16) & 1u)) >> 16);
}

// ---------------------------------------------------------------------------
// Sentinel fill (workspace-too-small diagnostic)
// ---------------------------------------------------------------------------
__global__ void fill_kernel(float* __restrict__ p, float val, int n)
{
    int i = blockIdx.x * blockDim.x + threadIdx.x;
    if (i < n) p[i] = val;
}

// ---------------------------------------------------------------------------
// Instance-norm stats per (b,c): mean over T, stdev = sqrt(var + 1e-5)
// ---------------------------------------------------------------------------
__global__ __launch_bounds__(256) void instnorm_stats_kernel(
    const float* __restrict__ x, float* __restrict__ means, float* __restrict__ stdev)
{
    int b = blockIdx.x;
    int c = threadIdx.x & 31;
    int g = threadIdx.x >> 5;   // 0..7
    float s = 0.f, sq = 0.f;
    for (int t = g; t < kT; t += 8) {
        float v = x[(size_t)(b * kT + t) * kC + c];
        s += v; sq += v * v;
    }
    __shared__ float ss[8][32], ssq[8][32];
    ss[g][c] = s; ssq[g][c] = sq;
    __syncthreads();
    if (g == 0) {
        float S = 0.f, SQ = 0.f;
        for (int i = 0; i < 8; i++) { S += ss[i][c]; SQ += ssq[i][c]; }
        float m = S / kT;
        float var = SQ / kT - m * m;
        means[b * kC + c] = m;
        stdev[b * kC + c] = sqrtf(var + 1e-5f);
    }
}

// ---------------------------------------------------------------------------
// Patch embed: tok[(r*64+n), d] = sum_p xn[t=n*8+p]*W_val[p,d] + pe[n,d] (bf16)
// ---------------------------------------------------------------------------
__global__ __launch_bounds__(256) void patch_embed_kernel(
    const float* __restrict__ x, const float* __restrict__ Wval,
    const float* __restrict__ means, const float* __restrict__ stdev,
    unsigned short* __restrict__ tok)
{
    int m = blockIdx.x;
    int r = m >> 6, n = m & 63;
    int b = r >> 5, c = r & 31;
    __shared__ float patch[kP];
    if (threadIdx.x < kP) {
        int t = n * kStride + threadIdx.x;
        if (t > kT - 1) t = kT - 1;   // replication pad
        patch[threadIdx.x] = (x[(size_t)(b * kT + t) * kC + c] - means[r]) / stdev[r];
    }
    __syncthreads();
    for (int d = threadIdx.x; d < kD; d += 256) {
        float acc = 0.f;
        #pragma unroll
        for (int p = 0; p < kP; p++) acc += patch[p] * Wval[p * kD + d];
        int j = d >> 1;
        float freq = expf(-(float)(2 * j) * (9.210340371976184f / (float)kD));
        float ang = (float)n * freq;
        float pe = (d & 1) ? cosf(ang) : sinf(ang);
        tok[(size_t)m * kD + d] = f2b(acc + pe);
    }
}

// ---------------------------------------------------------------------------
// GEMM: C[M,Nn] = A_bf16[M,K(lda)] @ B_f32[K,Nn(ldb)] + epilogue, C bf16
// BM=64 BN=64 BK=16, 256 threads, 4x4 microtile, fp32 accumulation.
// EPI: 0 = C = acc + bias
//      1 = C += acc (+ bias if non-null)   (residual, read-modify-write)
//      2 = C = gelu_exact(acc + bias)
// grid: (Nn/64, Mrows/64)
// ---------------------------------------------------------------------------
template<int EPI>
__global__ __launch_bounds__(256) void gemm_bf(
    const unsigned short* __restrict__ A, const float* __restrict__ Bm,
    const float* __restrict__ bias, unsigned short* __restrict__ Cout,
    int K, int lda, int ldb, int ldc)
{
    constexpr int BK = 16;
    __shared__ float As[BK][64];       // stored transposed: As[k][m]
    __shared__ float Bs[BK][64];
    const int tid = threadIdx.x;
    const int row0 = blockIdx.y * 64;
    const int col0 = blockIdx.x * 64;
    const int tx = tid & 15, ty = tid >> 4;
    const int m_a = tid >> 2, k_a = (tid & 3) * 4;   // A tile: 64 rows x 16 k
    const int k_b = tid >> 4, n_b = (tid & 15) * 4;  // B tile: 16 k x 64 n
    const unsigned short* Aptr = A + (size_t)(row0 + m_a) * lda + k_a;
    const float* Bptr = Bm + (size_t)k_b * ldb + col0 + n_b;
    float acc[4][4] = {};
    for (int k0 = 0; k0 < K; k0 += BK) {
        ushort4 av = *(const ushort4*)(Aptr + k0);
        float4 bv = *(const float4*)(Bptr + (size_t)k0 * ldb);
        __syncthreads();
        As[k_a + 0][m_a] = b2f(av.x); As[k_a + 1][m_a] = b2f(av.y);
        As[k_a + 2][m_a] = b2f(av.z); As[k_a + 3][m_a] = b2f(av.w);
        *(float4*)&Bs[k_b][n_b] = bv;
        __syncthreads();
        #pragma unroll
        for (int kk = 0; kk < BK; kk++) {
            float a[4], bb[4];
            #pragma unroll
            for (int i = 0; i < 4; i++) a[i] = As[kk][ty * 4 + i];
            #pragma unroll
            for (int j = 0; j < 4; j++) bb[j] = Bs[kk][tx * 4 + j];
            #pragma unroll
            for (int i = 0; i < 4; i++)
                #pragma unroll
                for (int j = 0; j < 4; j++)
                    acc[i][j] += a[i] * bb[j];
        }
    }
    #pragma unroll
    for (int i = 0; i < 4; i++) {
        int rr = row0 + ty * 4 + i;
        #pragma unroll
        for (int j = 0; j < 4; j++) {
            int cc = col0 + tx * 4 + j;
            float v = acc[i][j];
            size_t oidx = (size_t)rr * ldc + cc;
            if (EPI == 0) {
                Cout[oidx] = f2b(v + bias[cc]);
            } else if (EPI == 1) {
                float bb = bias ? bias[cc] : 0.f;
                Cout[oidx] = f2b(b2f(Cout[oidx]) + v + bb);
            } else {
                float z = v + bias[cc];
                Cout[oidx] = f2b(0.5f * z * (1.f + erff(z * 0.7071067811865475f)));
            }
        }
    }
}

// ---------------------------------------------------------------------------
// Attention per (head h, series r within chunk); q,k,v bf16 [chunkRows, 512],
// head slice h*64.. ; softmax fp32 in LDS; output written IN PLACE over q.
// grid: (kH, CH), block 256.
// ---------------------------------------------------------------------------
__global__ __launch_bounds__(256) void attn_kernel(
    unsigned short* __restrict__ qbuf, const unsigned short* __restrict__ kbuf,
    const unsigned short* __restrict__ vbuf)
{
    int h = blockIdx.x;
    int r = blockIdx.y;
    __shared__ float qs[64][65];   // q, later reused for v
    __shared__ float ks[64][65];
    __shared__ float sc[64][65];
    const int tid = threadIdx.x;
    const size_t base = (size_t)r * 64 * kD + h * 64;
    for (int idx = tid; idx < 64 * 64; idx += 256) {
        int n = idx >> 6, e = idx & 63;
        qs[n][e] = b2f(qbuf[base + (size_t)n * kD + e]);
        ks[n][e] = b2f(kbuf[base + (size_t)n * kD + e]);
    }
    __syncthreads();
    const int tx = tid & 15, ty = tid >> 4;
    float sacc[4][4] = {};
    for (int k = 0; k < 64; k++) {
        float a[4], b[4];
        #pragma unroll
        for (int i = 0; i < 4; i++) a[i] = qs[ty * 4 + i][k];
        #pragma unroll
        for (int j = 0; j < 4; j++) b[j] = ks[tx * 4 + j][k];
        #pragma unroll
        for (int i = 0; i < 4; i++)
            #pragma unroll
            for (int j = 0; j < 4; j++)
                sacc[i][j] += a[i] * b[j];
    }
    #pragma unroll
    for (int i = 0; i < 4; i++)
        #pragma unroll
        for (int j = 0; j < 4; j++)
            sc[ty * 4 + i][tx * 4 + j] = sacc[i][j] * 0.125f;
    __syncthreads();
    if (tid < 64) {   // wave 0: one softmax row per lane
        float mx = -1e30f;
        for (int s = 0; s < 64; s++) mx = fmaxf(mx, sc[tid][s]);
        float sum = 0.f;
        for (int s = 0; s < 64; s++) { float e = expf(sc[tid][s] - mx); sc[tid][s] = e; sum += e; }
        float inv = 1.f / sum;
        for (int s = 0; s < 64; s++) sc[tid][s] *= inv;
    }
    // reload v into qs (q fully consumed before the previous barrier)
    for (int idx = tid; idx < 64 * 64; idx += 256) {
        int n = idx >> 6, e = idx & 63;
        qs[n][e] = b2f(vbuf[base + (size_t)n * kD + e]);
    }
    __syncthreads();
    float oacc[4][4] = {};
    for (int s = 0; s < 64; s++) {
        float p[4], vv[4];
        #pragma unroll
        for (int i = 0; i < 4; i++) p[i] = sc[ty * 4 + i][s];
        #pragma unroll
        for (int j = 0; j < 4; j++) vv[j] = qs[s][tx * 4 + j];
        #pragma unroll
        for (int i = 0; i < 4; i++)
            #pragma unroll
            for (int j = 0; j < 4; j++)
                oacc[i][j] += p[i] * vv[j];
    }
    #pragma unroll
    for (int i = 0; i < 4; i++)
        #pragma unroll
        for (int j = 0; j < 4; j++)
            qbuf[base + (size_t)(ty * 4 + i) * kD + tx * 4 + j] = f2b(oacc[i][j]);
}

// ---------------------------------------------------------------------------
// Row LayerNorm over D=512, bf16 in/out, fp32 stats. One wave per row.
// In-place safe.  grid: rows.
// ---------------------------------------------------------------------------
__global__ __launch_bounds__(64) void ln_kernel(
    const unsigned short* __restrict__ x, const float* __restrict__ g,
    const float* __restrict__ bb, unsigned short* __restrict__ y)
{
    size_t row = blockIdx.x;
    int lane = threadIdx.x;
    float v[8];
    float s = 0.f;
    #pragma unroll
    for (int i = 0; i < 8; i++) {
        v[i] = b2f(x[row * kD + lane + i * 64]);
        s += v[i];
    }
    #pragma unroll
    for (int off = 32; off; off >>= 1) s += __shfl_xor(s, off);
    float mean = s * (1.f / kD);
    float sq = 0.f;
    #pragma unroll
    for (int i = 0; i < 8; i++) { float d = v[i] - mean; sq += d * d; }
    #pragma unroll
    for (int off = 32; off; off >>= 1) sq += __shfl_xor(sq, off);
    float inv = 1.f / sqrtf(sq * (1.f / kD) + 1e-5f);
    #pragma unroll
    for (int i = 0; i < 8; i++) {
        int d = lane + i * 64;
        y[row * kD + d] = f2b((v[i] - mean) * inv * g[d] + bb[d]);
    }
}

// ---------------------------------------------------------------------------
// BatchNorm stats (per channel d over all kM rows)
// ---------------------------------------------------------------------------
__global__ void zero_kernel(float* __restrict__ p, int n)
{
    int i = blockIdx.x * blockDim.x + threadIdx.x;
    if (i < n) p[i] = 0.f;
}

__global__ __launch_bounds__(512) void bn_stats_kernel(
    const unsigned short* __restrict__ tok, float* __restrict__ sums,
    float* __restrict__ sumsq)
{
    int d = threadIdx.x;
    float s = 0.f, sq = 0.f;
    int row0 = blockIdx.x * 256;
    for (int row = row0; row < row0 + 256; row++) {
        float v = b2f(tok[(size_t)row * kD + d]);
        s += v; sq += v * v;
    }
    atomicAdd(&sums[d], s);
    atomicAdd(&sumsq[d], sq);
}

__global__ __launch_bounds__(512) void bn_final_kernel(
    const float* __restrict__ sums, const float* __restrict__ sumsq,
    const float* __restrict__ g, const float* __restrict__ bb,
    float* __restrict__ scale, float* __restrict__ shift)
{
    int d = threadIdx.x;
    float mean = sums[d] / (float)kM;
    float var = sumsq[d] / (float)kM - mean * mean;
    float sc = g[d] / sqrtf(var + 1e-5f);
    scale[d] = sc;
    shift[d] = bb[d] - mean * sc;
}

// ---------------------------------------------------------------------------
// Head GEMM: out[b,t,c] = (enc[r,:] @ W_head[:,t] + b_head[t])*stdev[r]+means[r]
// where enc[r, d*64+n] = scale[d]*tok[(r*64+n),d] + shift[d]  (BN+transpose
// folded into the A-tile load; no enc buffer).
// A: M=kR rows, K = 512*64 = 32768. grid (kT/64, kR/64), block 256.
// ---------------------------------------------------------------------------
__global__ __launch_bounds__(256) void head_gemm_kernel(
    const unsigned short* __restrict__ tok, const float* __restrict__ Wh,
    const float* __restrict__ bias, float* __restrict__ out,
    const float* __restrict__ scale, const float* __restrict__ shift,
    const float* __restrict__ stdev, const float* __restrict__ means)
{
    constexpr int BK = 16;
    constexpr int K = kD * kN;   // 32768
    __shared__ float As[BK][64];
    __shared__ float Bs[BK][64];
    const int tid = threadIdx.x;
    const int row0 = blockIdx.y * 64;
    const int col0 = blockIdx.x * 64;
    const int tx = tid & 15, ty = tid >> 4;
    const int m_a = tid >> 2, k_a = (tid & 3) * 4;
    const int k_b = tid >> 4, n_b = (tid & 15) * 4;
    const int rA = row0 + m_a;                 // series index
    const float* Bptr = Wh + (size_t)k_b * kT + col0 + n_b;
    float acc[4][4] = {};
    for (int k0 = 0; k0 < K; k0 += BK) {
        int kk0 = k0 + k_a;
        int d = kk0 >> 6;          // same d for all 4 consecutive k (n 4-aligned)
        int n0 = kk0 & 63;
        float sc_d = scale[d], sh_d = shift[d];
        float a0 = sc_d * b2f(tok[(size_t)(rA * 64 + n0 + 0) * kD + d]) + sh_d;
        float a1 = sc_d * b2f(tok[(size_t)(rA * 64 + n0 + 1) * kD + d]) + sh_d;
        float a2 = sc_d * b2f(tok[(size_t)(rA * 64 + n0 + 2) * kD + d]) + sh_d;
        float a3 = sc_d * b2f(tok[(size_t)(rA * 64 + n0 + 3) * kD + d]) + sh_d;
        float4 bv = *(const float4*)(Bptr + (size_t)k0 * kT);
        __syncthreads();
        As[k_a + 0][m_a] = a0; As[k_a + 1][m_a] = a1;
        As[k_a + 2][m_a] = a2; As[k_a + 3][m_a] = a3;
        *(float4*)&Bs[k_b][n_b] = bv;
        __syncthreads();
        #pragma unroll
        for (int kk = 0; kk < BK; kk++) {
            float a[4], bb[4];
            #pragma unroll
            for (int i = 0; i < 4; i++) a[i] = As[kk][ty * 4 + i];
            #pragma unroll
            for (int j = 0; j < 4; j++) bb[j] = Bs[kk][tx * 4 + j];
            #pragma unroll
            for (int i = 0; i < 4; i++)
                #pragma unroll
                for (int j = 0; j < 4; j++)
                    acc[i][j] += a[i] * bb[j];
        }
    }
    #pragma unroll
    for (int i = 0; i < 4; i++) {
        int rr = row0 + ty * 4 + i;
        float sd = stdev[rr], mn = means[rr];
        int b = rr >> 5, c = rr & 31;
        #pragma unroll
        for (int j = 0; j < 4; j++) {
            int cc = col0 + tx * 4 + j;
            float z = (acc[i][j] + bias[cc]) * sd + mn;
            out[((size_t)(b * kT + cc)) * kC + c] = z;
        }
    }
}

// ---------------------------------------------------------------------------
// Launch
// ---------------------------------------------------------------------------
extern "C" void kernel_launch(void* const* d_in, const int* in_sizes, int n_in,
                              void* d_out, int out_size, void* d_ws, size_t ws_size,
                              hipStream_t stream)
{
    const float* x_enc  = (const float*)d_in[0];
    const float* W_val  = (const float*)d_in[1];
    const float* Wq     = (const float*)d_in[2];
    const float* bq     = (const float*)d_in[3];
    const float* Wk     = (const float*)d_in[4];
    const float* bk     = (const float*)d_in[5];
    const float* Wv     = (const float*)d_in[6];
    const float* bv     = (const float*)d_in[7];
    const float* Wo     = (const float*)d_in[8];
    const float* bo     = (const float*)d_in[9];
    const float* Wc1    = (const float*)d_in[10];
    const float* bc1    = (const float*)d_in[11];
    const float* Wc2    = (const float*)d_in[12];
    const float* bc2    = (const float*)d_in[13];
    const float* ln1_g  = (const float*)d_in[14];
    const float* ln1_b  = (const float*)d_in[15];
    const float* ln2_g  = (const float*)d_in[16];
    const float* ln2_b  = (const float*)d_in[17];
    const float* bn_g   = (const float*)d_in[18];
    const float* bn_b   = (const float*)d_in[19];
    const float* W_head = (const float*)d_in[20];
    const float* b_head = (const float*)d_in[21];
    float* out = (float*)d_out;

    // Workspace (bf16 activations):
    //   tok   [kM * 512] bf16                          = 67,108,864 B
    //   s0/s1/s2: 3 chunk-units bf16 (q|k|v, y|h-half) = 25,165,824 B
    //   fp32 tail: means/stdev [kR], bn sums/sq/scale/shift [kD]
    unsigned short* tokb = (unsigned short*)d_ws;
    unsigned short* s0 = tokb + (size_t)kM * kD;
    unsigned short* s1 = s0 + kChunkRows * kD;
    unsigned short* s2 = s1 + kChunkRows * kD;
    float* fbuf = (float*)(s0 + 3 * kChunkRows * kD);
    float* means    = fbuf;
    float* stdevp   = means + kR;
    float* bn_sums  = stdevp + kR;
    float* bn_sumsq = bn_sums + kD;
    float* bn_scale = bn_sumsq + kD;
    float* bn_shift = bn_scale + kD;
    const size_t need_bytes = (size_t)kM * kD * 2 + 3 * kChunkRows * kD * 2
                            + (2 * kR + 4 * kD) * sizeof(float);
    if (ws_size < need_bytes) {
        // distinctive sentinel so a ws-size failure is unambiguous
        hipLaunchKernelGGL(fill_kernel, dim3((out_size + 255) / 256), dim3(256), 0,
                           stream, out, 1.0e6f, out_size);
        return;
    }

    hipLaunchKernelGGL(instnorm_stats_kernel, dim3(kB), dim3(256), 0, stream,
                       x_enc, means, stdevp);
    hipLaunchKernelGGL(patch_embed_kernel, dim3(kM), dim3(256), 0, stream,
                       x_enc, W_val, means, stdevp, tokb);

    const dim3 blk(256);
    const dim3 g512(kD / 64, kChunkRows / 64);     // (8, 128)
    const dim3 g1024(1024 / 64, kChunkRows / 64);  // (16, 128)

    for (int ch = 0; ch < kNCH; ch++) {
        unsigned short* tokc = tokb + (size_t)ch * kChunkRows * kD;
        for (int i = 0; i < kNL; i++) {
            const float* Wq_i = Wq + (size_t)i * kD * kD;
            const float* Wk_i = Wk + (size_t)i * kD * kD;
            const float* Wv_i = Wv + (size_t)i * kD * kD;
            const float* Wo_i = Wo + (size_t)i * kD * kD;
            const float* Wc1_i = Wc1 + (size_t)i * kD * kDFF;
            const float* Wc2_i = Wc2 + (size_t)i * kDFF * kD;

            // QKV projections (A = tok chunk, bf16)
            hipLaunchKernelGGL(gemm_bf<0>, g512, blk, 0, stream,
                               tokc, Wq_i, bq + i * kD, s0, kD, kD, kD, kD);
            hipLaunchKernelGGL(gemm_bf<0>, g512, blk, 0, stream,
                               tokc, Wk_i, bk + i * kD, s1, kD, kD, kD, kD);
            hipLaunchKernelGGL(gemm_bf<0>, g512, blk, 0, stream,
                               tokc, Wv_i, bv + i * kD, s2, kD, kD, kD, kD);
            // attention (writes output over s0)
            hipLaunchKernelGGL(attn_kernel, dim3(kH, kCH), blk, 0, stream,
                               s0, s1, s2);
            // tok += attn_out @ Wo + bo
            hipLaunchKernelGGL(gemm_bf<1>, g512, blk, 0, stream,
                               s0, Wo_i, bo + i * kD, tokc, kD, kD, kD, kD);
            // y = LN1(tok) -> s0
            hipLaunchKernelGGL(ln_kernel, dim3((int)kChunkRows), dim3(64), 0, stream,
                               tokc, ln1_g + i * kD, ln1_b + i * kD, s0);
            // FFN half A: cols [0,1024) of DFF; h -> s1..s2 (2 units)
            hipLaunchKernelGGL(gemm_bf<2>, g1024, blk, 0, stream,
                               s0, Wc1_i, bc1 + (size_t)i * kDFF, s1,
                               kD, kD, kDFF, 1024);
            hipLaunchKernelGGL(gemm_bf<1>, g512, blk, 0, stream,
                               s1, Wc2_i, bc2 + i * kD, tokc, 1024, 1024, kD, kD);
            // FFN half B: cols [1024,2048)
            hipLaunchKernelGGL(gemm_bf<2>, g1024, blk, 0, stream,
                               s0, Wc1_i + 1024, bc1 + (size_t)i * kDFF + 1024, s1,
                               kD, kD, kDFF, 1024);
            hipLaunchKernelGGL(gemm_bf<1>, g512, blk, 0, stream,
                               s1, Wc2_i + (size_t)1024 * kD, nullptr, tokc,
                               1024, 1024, kD, kD);
            // tok = LN2(tok) in place
            hipLaunchKernelGGL(ln_kernel, dim3((int)kChunkRows), dim3(64), 0, stream,
                               tokc, ln2_g + i * kD, ln2_b + i * kD, tokc);
        }
    }

    // BatchNorm over all rows per channel
    hipLaunchKernelGGL(zero_kernel, dim3(1), dim3(1024), 0, stream, bn_sums, 2 * kD);
    hipLaunchKernelGGL(bn_stats_kernel, dim3(kM / 256), dim3(512), 0, stream,
                       tokb, bn_sums, bn_sumsq);
    hipLaunchKernelGGL(bn_final_kernel, dim3(1), dim3(512), 0, stream,
                       bn_sums, bn_sumsq, bn_g, bn_b, bn_scale, bn_shift);
    // head GEMM with BN + transpose folded into A-load, instnorm-denorm epilogue
    hipLaunchKernelGGL(head_gemm_kernel, dim3(kT / 64, kR / 64), blk, 0, stream,
                       tokb, W_head, b_head, out, bn_scale, bn_shift,
                       stdevp, means);
}

// Round 3
// 5967.521 us; speedup vs baseline: 3.9994x; 3.9994x over previous
//
#include <hip/hip_runtime.h>
#include <math.h>

// ---------------------------------------------------------------------------
// Problem constants (PatchTST-style transformer)
// ---------------------------------------------------------------------------
namespace {
constexpr int kB = 32, kT = 512, kC = 32, kD = 512, kDFF = 2048, kNL = 3;
constexpr int kP = 16, kStride = 8, kN = 64;
constexpr int kR = kB * kC;      // 1024 independent (b,c) series
constexpr int kM = kR * kN;      // 65536 tokens total
constexpr int kCH = 128;         // series per chunk
constexpr int kNCH = kR / kCH;   // 8 chunks
constexpr size_t kChunkRows = (size_t)kCH * kN;   // 8192
constexpr size_t kUnit = kChunkRows * kD;         // 4,194,304 elems (8.4MB bf16)
}

typedef unsigned short u16;
typedef __attribute__((ext_vector_type(8))) short short8;   // 8 bf16 (4 VGPRs)
typedef __attribute__((ext_vector_type(4))) float f32x4;    // MFMA accumulator

__device__ __forceinline__ float b2f(u16 u) {
    return __uint_as_float(((unsigned int)u) << 16);
}
__device__ __forceinline__ u16 f2b(float f) {
    unsigned int x = __float_as_uint(f);
    return (u16)((x + 0x7fffu + ((x >> 16) & 1u)) >> 16);
}

// async global->LDS, 16B per lane. lds ptr must be wave-uniform base.
__device__ __forceinline__ void async_copy16(const void* g, void* l) {
    __builtin_amdgcn_global_load_lds(
        (const __attribute__((address_space(1))) unsigned int*)g,
        (__attribute__((address_space(3))) unsigned int*)l, 16, 0, 0);
}

// ---------------------------------------------------------------------------
// Sentinel fill (workspace-too-small diagnostic)
// ---------------------------------------------------------------------------
__global__ void fill_kernel(float* __restrict__ p, float val, int n)
{
    int i = blockIdx.x * blockDim.x + threadIdx.x;
    if (i < n) p[i] = val;
}

// ---------------------------------------------------------------------------
// Instance-norm stats per (b,c)
// ---------------------------------------------------------------------------
__global__ __launch_bounds__(256) void instnorm_stats_kernel(
    const float* __restrict__ x, float* __restrict__ means, float* __restrict__ stdev)
{
    int b = blockIdx.x;
    int c = threadIdx.x & 31;
    int g = threadIdx.x >> 5;
    float s = 0.f, sq = 0.f;
    for (int t = g; t < kT; t += 8) {
        float v = x[(size_t)(b * kT + t) * kC + c];
        s += v; sq += v * v;
    }
    __shared__ float ss[8][32], ssq[8][32];
    ss[g][c] = s; ssq[g][c] = sq;
    __syncthreads();
    if (g == 0) {
        float S = 0.f, SQ = 0.f;
        for (int i = 0; i < 8; i++) { S += ss[i][c]; SQ += ssq[i][c]; }
        float m = S / kT;
        float var = SQ / kT - m * m;
        means[b * kC + c] = m;
        stdev[b * kC + c] = sqrtf(var + 1e-5f);
    }
}

// ---------------------------------------------------------------------------
// Patch embed (bf16 out)
// ---------------------------------------------------------------------------
__global__ __launch_bounds__(256) void patch_embed_kernel(
    const float* __restrict__ x, const float* __restrict__ Wval,
    const float* __restrict__ means, const float* __restrict__ stdev,
    u16* __restrict__ tok)
{
    int m = blockIdx.x;
    int r = m >> 6, n = m & 63;
    int b = r >> 5, c = r & 31;
    __shared__ float patch[kP];
    if (threadIdx.x < kP) {
        int t = n * kStride + threadIdx.x;
        if (t > kT - 1) t = kT - 1;
        patch[threadIdx.x] = (x[(size_t)(b * kT + t) * kC + c] - means[r]) / stdev[r];
    }
    __syncthreads();
    for (int d = threadIdx.x; d < kD; d += 256) {
        float acc = 0.f;
        #pragma unroll
        for (int p = 0; p < kP; p++) acc += patch[p] * Wval[p * kD + d];
        int j = d >> 1;
        float freq = expf(-(float)(2 * j) * (9.210340371976184f / (float)kD));
        float ang = (float)n * freq;
        float pe = (d & 1) ? cosf(ang) : sinf(ang);
        tok[(size_t)m * kD + d] = f2b(acc + pe);
    }
}

// ---------------------------------------------------------------------------
// Transpose + fp32->bf16 convert: out[n*ldo + k] = f2b(in[k*ldi + n])
// per z-slice: in += z*zin, out += z*zout.  grid (K/64, N/64, Z), 256 thr.
// ---------------------------------------------------------------------------
__global__ __launch_bounds__(256) void transpose_cvt_kernel(
    const float* __restrict__ in, u16* __restrict__ outp,
    int ldi, int ldo, int zin, int zout)
{
    __shared__ float tile[64][65];
    const float* ib = in + (size_t)blockIdx.z * zin;
    u16* ob = outp + (size_t)blockIdx.z * zout;
    int k0 = blockIdx.x * 64, n0 = blockIdx.y * 64;
    int tn = threadIdx.x & 63, tk0 = threadIdx.x >> 6;
    #pragma unroll
    for (int kk = tk0; kk < 64; kk += 4)
        tile[kk][tn] = ib[(size_t)(k0 + kk) * ldi + n0 + tn];
    __syncthreads();
    int wk = threadIdx.x & 63, wn0 = threadIdx.x >> 6;
    #pragma unroll
    for (int nn = wn0; nn < 64; nn += 4)
        ob[(size_t)(n0 + nn) * ldo + k0 + wk] = f2b(tile[wk][nn]);
}

// ---------------------------------------------------------------------------
// MFMA bf16 GEMM, 128x128 tile, BK=32, 256 thr (4 waves 2x2), m97 structure.
// A: [M][lda] bf16 row-major.  B: [N][ldb] bf16 N-MAJOR (row n = output col).
// grid: (N/128, M/128, Z) — Z>1 = split-K (global k = z*K + kb), EPI 3 only.
// EPI 0: qkv — dst/bias selected by col block: C0/C1/C2, bias/auxb1/auxb2
// EPI 1: C0[r*ldc+c] += acc + (bias?bias[c]:0)       (bf16 rmw)
// EPI 2: C0[r*ldc+c]  = gelu_erf(acc + bias[c])
// EPI 3: atomicAdd(fout[((r>>5)*512+c)*32 + (r&31)], acc*stdev[r])
// ---------------------------------------------------------------------------
template<int EPI>
__global__ __launch_bounds__(256) void mfma_gemm(
    const u16* __restrict__ A, const u16* __restrict__ B,
    const float* __restrict__ bias, const float* __restrict__ auxb1,
    const float* __restrict__ auxb2,
    u16* __restrict__ C0, u16* __restrict__ C1, u16* __restrict__ C2,
    float* __restrict__ fout, const float* __restrict__ stdev,
    int K, int lda, int ldb, int ldc)
{
    __shared__ u16 As[128 * 32];
    __shared__ u16 Bs[128 * 32];
    const int tid = threadIdx.x;
    const int lane = tid & 63;
    const int wave = tid >> 6;
    const int row0 = blockIdx.y * 128;
    const int col0 = blockIdx.x * 128;
    const size_t zoff = (size_t)blockIdx.z * K;

    // staging map: wave w stages rows w*16..w*16+15 (and +64), lane i -> 16B
    const int stRow = (wave << 4) + (lane >> 2);
    const int stCol = (lane & 3) << 3;
    const u16* Ag = A + (size_t)(row0 + stRow) * lda + zoff + stCol;
    const u16* Bg = B + (size_t)(col0 + stRow) * ldb + zoff + stCol;
    u16* AsW = As + (wave << 4) * 32;
    u16* BsW = Bs + (wave << 4) * 32;

    const int fm = lane & 15;
    const int fk = (lane >> 4) << 3;
    const int wm = wave & 1, wn = wave >> 1;

    f32x4 acc[4][4];
    #pragma unroll
    for (int i = 0; i < 4; i++)
        #pragma unroll
        for (int j = 0; j < 4; j++)
            acc[i][j] = (f32x4){0.f, 0.f, 0.f, 0.f};

    for (int kb = 0; kb < K; kb += 32) {
        __syncthreads();
        async_copy16(Ag + kb, AsW);
        async_copy16(Ag + kb + (size_t)64 * lda, AsW + 64 * 32);
        async_copy16(Bg + kb, BsW);
        async_copy16(Bg + kb + (size_t)64 * ldb, BsW + 64 * 32);
        __syncthreads();
        short8 af[4], bfr[4];
        #pragma unroll
        for (int mi = 0; mi < 4; mi++)
            af[mi] = *(const short8*)&As[((wm << 6) + (mi << 4) + fm) * 32 + fk];
        #pragma unroll
        for (int ni = 0; ni < 4; ni++)
            bfr[ni] = *(const short8*)&Bs[((wn << 6) + (ni << 4) + fm) * 32 + fk];
        #pragma unroll
        for (int mi = 0; mi < 4; mi++)
            #pragma unroll
            for (int ni = 0; ni < 4; ni++)
                acc[mi][ni] = __builtin_amdgcn_mfma_f32_16x16x32_bf16(
                    af[mi], bfr[ni], acc[mi][ni], 0, 0, 0);
    }

    // epilogue: C/D layout col=lane&15, row=(lane>>4)*4+i  [m89-verified]
    const int er = (lane >> 4) << 2;
    const int ec = lane & 15;
    u16* dsel = C0;
    const float* bsel = bias;
    if (EPI == 0) {
        int sub = col0 >> 9;
        dsel = (sub == 0) ? C0 : ((sub == 1) ? C1 : C2);
        bsel = (sub == 0) ? bias : ((sub == 1) ? auxb1 : auxb2);
    }
    #pragma unroll
    for (int mi = 0; mi < 4; mi++) {
        #pragma unroll
        for (int ni = 0; ni < 4; ni++) {
            #pragma unroll
            for (int i = 0; i < 4; i++) {
                int r = row0 + (wm << 6) + (mi << 4) + er + i;
                int cc = col0 + (wn << 6) + (ni << 4) + ec;
                float v = acc[mi][ni][i];
                if (EPI == 0) {
                    int cl = cc & 511;
                    dsel[(size_t)r * 512 + cl] = f2b(v + bsel[cl]);
                } else if (EPI == 1) {
                    size_t o = (size_t)r * ldc + cc;
                    float bb = bias ? bias[cc] : 0.f;
                    C0[o] = f2b(b2f(C0[o]) + v + bb);
                } else if (EPI == 2) {
                    size_t o = (size_t)r * ldc + cc;
                    float z = v + bias[cc];
                    C0[o] = f2b(0.5f * z * (1.f + erff(z * 0.7071067811865475f)));
                } else {
                    float vv = v * stdev[r];
                    atomicAdd(&fout[(((size_t)(r >> 5) * kT + cc) << 5) + (r & 31)], vv);
                }
            }
        }
    }
}

// ---------------------------------------------------------------------------
// Attention per (head h, series r in chunk); in-place over q. grid (8, kCH).
// ---------------------------------------------------------------------------
__global__ __launch_bounds__(256) void attn_kernel(
    u16* __restrict__ qbuf, const u16* __restrict__ kbuf,
    const u16* __restrict__ vbuf)
{
    int h = blockIdx.x;
    int r = blockIdx.y;
    __shared__ float qs[64][65];
    __shared__ float ks[64][65];
    __shared__ float sc[64][65];
    const int tid = threadIdx.x;
    const size_t base = (size_t)r * 64 * kD + h * 64;
    for (int idx = tid; idx < 64 * 64; idx += 256) {
        int n = idx >> 6, e = idx & 63;
        qs[n][e] = b2f(qbuf[base + (size_t)n * kD + e]);
        ks[n][e] = b2f(kbuf[base + (size_t)n * kD + e]);
    }
    __syncthreads();
    const int tx = tid & 15, ty = tid >> 4;
    float sacc[4][4] = {};
    for (int k = 0; k < 64; k++) {
        float a[4], b[4];
        #pragma unroll
        for (int i = 0; i < 4; i++) a[i] = qs[ty * 4 + i][k];
        #pragma unroll
        for (int j = 0; j < 4; j++) b[j] = ks[tx * 4 + j][k];
        #pragma unroll
        for (int i = 0; i < 4; i++)
            #pragma unroll
            for (int j = 0; j < 4; j++)
                sacc[i][j] += a[i] * b[j];
    }
    #pragma unroll
    for (int i = 0; i < 4; i++)
        #pragma unroll
        for (int j = 0; j < 4; j++)
            sc[ty * 4 + i][tx * 4 + j] = sacc[i][j] * 0.125f;
    __syncthreads();
    if (tid < 64) {
        float mx = -1e30f;
        for (int s = 0; s < 64; s++) mx = fmaxf(mx, sc[tid][s]);
        float sum = 0.f;
        for (int s = 0; s < 64; s++) { float e = expf(sc[tid][s] - mx); sc[tid][s] = e; sum += e; }
        float inv = 1.f / sum;
        for (int s = 0; s < 64; s++) sc[tid][s] *= inv;
    }
    for (int idx = tid; idx < 64 * 64; idx += 256) {
        int n = idx >> 6, e = idx & 63;
        qs[n][e] = b2f(vbuf[base + (size_t)n * kD + e]);
    }
    __syncthreads();
    float oacc[4][4] = {};
    for (int s = 0; s < 64; s++) {
        float p[4], vv[4];
        #pragma unroll
        for (int i = 0; i < 4; i++) p[i] = sc[ty * 4 + i][s];
        #pragma unroll
        for (int j = 0; j < 4; j++) vv[j] = qs[s][tx * 4 + j];
        #pragma unroll
        for (int i = 0; i < 4; i++)
            #pragma unroll
            for (int j = 0; j < 4; j++)
                oacc[i][j] += p[i] * vv[j];
    }
    #pragma unroll
    for (int i = 0; i < 4; i++)
        #pragma unroll
        for (int j = 0; j < 4; j++)
            qbuf[base + (size_t)(ty * 4 + i) * kD + tx * 4 + j] = f2b(oacc[i][j]);
}

// ---------------------------------------------------------------------------
// Row LayerNorm over D=512, bf16 in/out, in-place safe. One wave per row.
// ---------------------------------------------------------------------------
__global__ __launch_bounds__(64) void ln_kernel(
    const u16* __restrict__ x, const float* __restrict__ g,
    const float* __restrict__ bb, u16* __restrict__ y)
{
    size_t row = blockIdx.x;
    int lane = threadIdx.x;
    float v[8];
    float s = 0.f;
    #pragma unroll
    for (int i = 0; i < 8; i++) {
        v[i] = b2f(x[row * kD + lane + i * 64]);
        s += v[i];
    }
    #pragma unroll
    for (int off = 32; off; off >>= 1) s += __shfl_xor(s, off);
    float mean = s * (1.f / kD);
    float sq = 0.f;
    #pragma unroll
    for (int i = 0; i < 8; i++) { float d = v[i] - mean; sq += d * d; }
    #pragma unroll
    for (int off = 32; off; off >>= 1) sq += __shfl_xor(sq, off);
    float inv = 1.f / sqrtf(sq * (1.f / kD) + 1e-5f);
    #pragma unroll
    for (int i = 0; i < 8; i++) {
        int d = lane + i * 64;
        y[row * kD + d] = f2b((v[i] - mean) * inv * g[d] + bb[d]);
    }
}

// ---------------------------------------------------------------------------
// BatchNorm pieces
// ---------------------------------------------------------------------------
__global__ void zero_kernel(float* __restrict__ p, int n)
{
    int i = blockIdx.x * blockDim.x + threadIdx.x;
    if (i < n) p[i] = 0.f;
}

__global__ __launch_bounds__(512) void bn_stats_kernel(
    const u16* __restrict__ tok, float* __restrict__ sums, float* __restrict__ sumsq)
{
    int d = threadIdx.x;
    float s = 0.f, sq = 0.f;
    int row0 = blockIdx.x * 256;
    for (int row = row0; row < row0 + 256; row++) {
        float v = b2f(tok[(size_t)row * kD + d]);
        s += v; sq += v * v;
    }
    atomicAdd(&sums[d], s);
    atomicAdd(&sumsq[d], sq);
}

__global__ __launch_bounds__(512) void bn_final_kernel(
    const float* __restrict__ sums, const float* __restrict__ sumsq,
    const float* __restrict__ g, const float* __restrict__ bb,
    float* __restrict__ scale, float* __restrict__ shift)
{
    int d = threadIdx.x;
    float mean = sums[d] / (float)kM;
    float var = sumsq[d] / (float)kM - mean * mean;
    float sc = g[d] / sqrtf(var + 1e-5f);
    scale[d] = sc;
    shift[d] = bb[d] - mean * sc;
}

// in-place BN on tok (bf16)
__global__ __launch_bounds__(256) void bn_apply_kernel(
    u16* __restrict__ tok, const float* __restrict__ scale,
    const float* __restrict__ shift)
{
    size_t i = (size_t)blockIdx.x * 256 + threadIdx.x;
    int d = (int)(i & 511);
    tok[i] = f2b(b2f(tok[i]) * scale[d] + shift[d]);
}

// out[(b*T+t)*C+c] = b_head[t]*stdev[r]+means[r]  (split-K partials add onto it)
__global__ __launch_bounds__(256) void head_init_kernel(
    float* __restrict__ out, const float* __restrict__ b_head,
    const float* __restrict__ stdev, const float* __restrict__ means)
{
    int i = blockIdx.x * 256 + threadIdx.x;
    int c = i & 31, t = (i >> 5) & 511, b = i >> 14;
    int r = b * 32 + c;
    out[i] = b_head[t] * stdev[r] + means[r];
}

// ---------------------------------------------------------------------------
// Launch
// ---------------------------------------------------------------------------
extern "C" void kernel_launch(void* const* d_in, const int* in_sizes, int n_in,
                              void* d_out, int out_size, void* d_ws, size_t ws_size,
                              hipStream_t stream)
{
    const float* x_enc  = (const float*)d_in[0];
    const float* W_val  = (const float*)d_in[1];
    const float* Wq     = (const float*)d_in[2];
    const float* bq     = (const float*)d_in[3];
    const float* Wk     = (const float*)d_in[4];
    const float* bk     = (const float*)d_in[5];
    const float* Wv     = (const float*)d_in[6];
    const float* bv     = (const float*)d_in[7];
    const float* Wo     = (const float*)d_in[8];
    const float* bo     = (const float*)d_in[9];
    const float* Wc1    = (const float*)d_in[10];
    const float* bc1    = (const float*)d_in[11];
    const float* Wc2    = (const float*)d_in[12];
    const float* bc2    = (const float*)d_in[13];
    const float* ln1_g  = (const float*)d_in[14];
    const float* ln1_b  = (const float*)d_in[15];
    const float* ln2_g  = (const float*)d_in[16];
    const float* ln2_b  = (const float*)d_in[17];
    const float* bn_g   = (const float*)d_in[18];
    const float* bn_b   = (const float*)d_in[19];
    const float* W_head = (const float*)d_in[20];
    const float* b_head = (const float*)d_in[21];
    float* out = (float*)d_out;

    // Workspace (bf16):
    //   tokb [kM*512]                              67.1 MB
    //   S region (16,777,216 elems = 33.55 MB):
    //     layers: s0|s1|s2 (3 x kUnit) + wbL (3,145,728)
    //     head:   wbH = W_head bf16 k-permuted [512][32768]  (overlays S)
    //   fp32 tail: means/stdev [kR], bn sums/sq/scale/shift [kD]
    u16* tokb = (u16*)d_ws;
    u16* s0  = tokb + (size_t)kM * kD;
    u16* s1  = s0 + kUnit;
    u16* s2  = s1 + kUnit;
    u16* wbL = s2 + kUnit;
    u16* wbH = s0;
    u16* wQKV = wbL;                       // [1536][512]
    u16* wO   = wQKV + 1536 * 512;         // [512][512]
    u16* wC1  = wO + 512 * 512;            // [2048][512]
    u16* wC2  = wC1 + 2048 * 512;          // [512][2048]
    float* tail = (float*)(s0 + (size_t)512 * 32768);
    float* means    = tail;
    float* stdevp   = means + kR;
    float* bn_sums  = stdevp + kR;
    float* bn_sumsq = bn_sums + kD;
    float* bn_scale = bn_sumsq + kD;
    float* bn_shift = bn_scale + kD;
    const size_t need_bytes = ((size_t)kM * kD + (size_t)512 * 32768) * 2
                            + (2 * kR + 4 * kD) * sizeof(float);
    if (ws_size < need_bytes) {
        hipLaunchKernelGGL(fill_kernel, dim3((out_size + 255) / 256), dim3(256), 0,
                           stream, out, 1.0e6f, out_size);
        return;
    }

    hipLaunchKernelGGL(instnorm_stats_kernel, dim3(kB), dim3(256), 0, stream,
                       x_enc, means, stdevp);
    hipLaunchKernelGGL(patch_embed_kernel, dim3(kM), dim3(256), 0, stream,
                       x_enc, W_val, means, stdevp, tokb);

    const dim3 blk(256);
    const dim3 tr8(8, 8, 1);

    for (int i = 0; i < kNL; i++) {
        const float* Wq_i = Wq + (size_t)i * kD * kD;
        const float* Wk_i = Wk + (size_t)i * kD * kD;
        const float* Wv_i = Wv + (size_t)i * kD * kD;
        const float* Wo_i = Wo + (size_t)i * kD * kD;
        const float* Wc1_i = Wc1 + (size_t)i * kD * kDFF;
        const float* Wc2_i = Wc2 + (size_t)i * kDFF * kD;
        const float* bq_i = bq + i * kD, *bk_i = bk + i * kD, *bv_i = bv + i * kD;

        // weight convert+transpose into bf16 n-major buffers
        hipLaunchKernelGGL(transpose_cvt_kernel, tr8, blk, 0, stream,
                           Wq_i, wQKV, kD, kD, 0, 0);
        hipLaunchKernelGGL(transpose_cvt_kernel, tr8, blk, 0, stream,
                           Wk_i, wQKV + (size_t)512 * 512, kD, kD, 0, 0);
        hipLaunchKernelGGL(transpose_cvt_kernel, tr8, blk, 0, stream,
                           Wv_i, wQKV + (size_t)1024 * 512, kD, kD, 0, 0);
        hipLaunchKernelGGL(transpose_cvt_kernel, tr8, blk, 0, stream,
                           Wo_i, wO, kD, kD, 0, 0);
        hipLaunchKernelGGL(transpose_cvt_kernel, dim3(8, 32, 1), blk, 0, stream,
                           Wc1_i, wC1, kDFF, kD, 0, 0);
        hipLaunchKernelGGL(transpose_cvt_kernel, dim3(32, 8, 1), blk, 0, stream,
                           Wc2_i, wC2, kD, kDFF, 0, 0);

        for (int ch = 0; ch < kNCH; ch++) {
            u16* tokc = tokb + (size_t)ch * kChunkRows * kD;
            // fused QKV: N=1536, routed to s0/s1/s2
            hipLaunchKernelGGL(mfma_gemm<0>, dim3(12, 64, 1), blk, 0, stream,
                               tokc, wQKV, bq_i, bk_i, bv_i, s0, s1, s2,
                               nullptr, nullptr, kD, kD, kD, kD);
            hipLaunchKernelGGL(attn_kernel, dim3(8, kCH), blk, 0, stream,
                               s0, s1, s2);
            // tok += attn_out @ Wo + bo
            hipLaunchKernelGGL(mfma_gemm<1>, dim3(4, 64, 1), blk, 0, stream,
                               s0, wO, bo + i * kD, nullptr, nullptr,
                               tokc, nullptr, nullptr, nullptr, nullptr,
                               kD, kD, kD, kD);
            // y = LN1(tok) -> s0
            hipLaunchKernelGGL(ln_kernel, dim3((int)kChunkRows), dim3(64), 0, stream,
                               tokc, ln1_g + i * kD, ln1_b + i * kD, s0);
            // FFN in two DFF/2 halves; h lives in s1:s2 (2 units)
            for (int half = 0; half < 2; half++) {
                const u16* wc1h = wC1 + (size_t)half * 1024 * 512;
                const u16* wc2h = wC2 + (size_t)half * 1024;   // k-offset
                const float* bc1h = bc1 + (size_t)i * kDFF + half * 1024;
                hipLaunchKernelGGL(mfma_gemm<2>, dim3(8, 64, 1), blk, 0, stream,
                                   s0, wc1h, bc1h, nullptr, nullptr,
                                   s1, nullptr, nullptr, nullptr, nullptr,
                                   kD, kD, kD, 1024);
                hipLaunchKernelGGL(mfma_gemm<1>, dim3(4, 64, 1), blk, 0, stream,
                                   s1, wc2h, (half == 0) ? (bc2 + i * kD) : nullptr,
                                   nullptr, nullptr, tokc, nullptr, nullptr,
                                   nullptr, nullptr, 1024, 1024, kDFF, kD);
            }
            // tok = LN2(tok) in place
            hipLaunchKernelGGL(ln_kernel, dim3((int)kChunkRows), dim3(64), 0, stream,
                               tokc, ln2_g + i * kD, ln2_b + i * kD, tokc);
        }
    }

    // BatchNorm (stats -> apply in place on tok)
    hipLaunchKernelGGL(zero_kernel, dim3(1), dim3(1024), 0, stream, bn_sums, 2 * kD);
    hipLaunchKernelGGL(bn_stats_kernel, dim3(kM / 256), dim3(512), 0, stream,
                       tokb, bn_sums, bn_sumsq);
    hipLaunchKernelGGL(bn_final_kernel, dim3(1), dim3(512), 0, stream,
                       bn_sums, bn_sumsq, bn_g, bn_b, bn_scale, bn_shift);
    hipLaunchKernelGGL(bn_apply_kernel, dim3((int)((size_t)kM * kD / 256)), blk, 0,
                       stream, tokb, bn_scale, bn_shift);

    // head weights: wbH[t][n*512+d] = W_head[(d*64+n)*512+t]  (k' = n*512+d)
    hipLaunchKernelGGL(transpose_cvt_kernel, dim3(8, 8, 64), blk, 0, stream,
                       W_head, wbH, 64 * 512, 32768, 512, 512);
    // out = b_head*stdev+mean, then split-K MFMA adds acc*stdev
    hipLaunchKernelGGL(head_init_kernel, dim3(out_size / 256), blk, 0, stream,
                       out, b_head, stdevp, means);
    // A = tok viewed as [1024][32768] (k'=n*512+d is the flat tok order)
    hipLaunchKernelGGL(mfma_gemm<3>, dim3(4, 8, 8), blk, 0, stream,
                       tokb, wbH, nullptr, nullptr, nullptr,
                       nullptr, nullptr, nullptr, out, stdevp,
                       4096, 32768, 32768, kT);
}

// Round 4
// 3879.594 us; speedup vs baseline: 6.1518x; 1.5382x over previous
//
#include <hip/hip_runtime.h>
#include <math.h>

// ---------------------------------------------------------------------------
// Problem constants (PatchTST-style transformer)
// ---------------------------------------------------------------------------
namespace {
constexpr int kB = 32, kT = 512, kC = 32, kD = 512, kDFF = 2048, kNL = 3;
constexpr int kP = 16, kStride = 8, kN = 64;
constexpr int kR = kB * kC;      // 1024 independent (b,c) series
constexpr int kM = kR * kN;      // 65536 tokens total
constexpr size_t kWbElems = (size_t)1536 * 512 + 512 * 512 + 2048 * 512 + 512 * 2048;
}

typedef unsigned short u16;
typedef __attribute__((ext_vector_type(8))) short short8;   // 8 bf16 (4 VGPRs)
typedef __attribute__((ext_vector_type(4))) float f32x4;    // MFMA accumulator

__device__ __forceinline__ float b2f(u16 u) {
    return __uint_as_float(((unsigned int)u) << 16);
}
__device__ __forceinline__ u16 f2b(float f) {
    unsigned int x = __float_as_uint(f);
    return (u16)((x + 0x7fffu + ((x >> 16) & 1u)) >> 16);
}

// async global->LDS, 16B per lane. lds ptr must be wave-uniform base.
__device__ __forceinline__ void async_copy16(const void* g, void* l) {
    __builtin_amdgcn_global_load_lds(
        (const __attribute__((address_space(1))) unsigned int*)g,
        (__attribute__((address_space(3))) unsigned int*)l, 16, 0, 0);
}

// ---------------------------------------------------------------------------
// Sentinel fill (workspace-too-small diagnostic)
// ---------------------------------------------------------------------------
__global__ void fill_kernel(float* __restrict__ p, float val, int n)
{
    int i = blockIdx.x * blockDim.x + threadIdx.x;
    if (i < n) p[i] = val;
}

// ---------------------------------------------------------------------------
// Instance-norm stats per (b,c)
// ---------------------------------------------------------------------------
__global__ __launch_bounds__(256) void instnorm_stats_kernel(
    const float* __restrict__ x, float* __restrict__ means, float* __restrict__ stdev)
{
    int b = blockIdx.x;
    int c = threadIdx.x & 31;
    int g = threadIdx.x >> 5;
    float s = 0.f, sq = 0.f;
    for (int t = g; t < kT; t += 8) {
        float v = x[(size_t)(b * kT + t) * kC + c];
        s += v; sq += v * v;
    }
    __shared__ float ss[8][32], ssq[8][32];
    ss[g][c] = s; ssq[g][c] = sq;
    __syncthreads();
    if (g == 0) {
        float S = 0.f, SQ = 0.f;
        for (int i = 0; i < 8; i++) { S += ss[i][c]; SQ += ssq[i][c]; }
        float m = S / kT;
        float var = SQ / kT - m * m;
        means[b * kC + c] = m;
        stdev[b * kC + c] = sqrtf(var + 1e-5f);
    }
}

// ---------------------------------------------------------------------------
// Patch embed (bf16 out)
// ---------------------------------------------------------------------------
__global__ __launch_bounds__(256) void patch_embed_kernel(
    const float* __restrict__ x, const float* __restrict__ Wval,
    const float* __restrict__ means, const float* __restrict__ stdev,
    u16* __restrict__ tok)
{
    int m = blockIdx.x;
    int r = m >> 6, n = m & 63;
    int b = r >> 5, c = r & 31;
    __shared__ float patch[kP];
    if (threadIdx.x < kP) {
        int t = n * kStride + threadIdx.x;
        if (t > kT - 1) t = kT - 1;
        patch[threadIdx.x] = (x[(size_t)(b * kT + t) * kC + c] - means[r]) / stdev[r];
    }
    __syncthreads();
    for (int d = threadIdx.x; d < kD; d += 256) {
        float acc = 0.f;
        #pragma unroll
        for (int p = 0; p < kP; p++) acc += patch[p] * Wval[p * kD + d];
        int j = d >> 1;
        float freq = expf(-(float)(2 * j) * (9.210340371976184f / (float)kD));
        float ang = (float)n * freq;
        float pe = (d & 1) ? cosf(ang) : sinf(ang);
        tok[(size_t)m * kD + d] = f2b(acc + pe);
    }
}

// ---------------------------------------------------------------------------
// Transpose + fp32->bf16 convert: out[n*ldo + k] = f2b(in[k*ldi + n])
// per z-slice: in += z*zin, out += z*zout.  grid (K/64, N/64, Z), 256 thr.
// ---------------------------------------------------------------------------
__global__ __launch_bounds__(256) void transpose_cvt_kernel(
    const float* __restrict__ in, u16* __restrict__ outp,
    int ldi, int ldo, int zin, int zout)
{
    __shared__ float tile[64][65];
    const float* ib = in + (size_t)blockIdx.z * zin;
    u16* ob = outp + (size_t)blockIdx.z * zout;
    int k0 = blockIdx.x * 64, n0 = blockIdx.y * 64;
    int tn = threadIdx.x & 63, tk0 = threadIdx.x >> 6;
    #pragma unroll
    for (int kk = tk0; kk < 64; kk += 4)
        tile[kk][tn] = ib[(size_t)(k0 + kk) * ldi + n0 + tn];
    __syncthreads();
    int wk = threadIdx.x & 63, wn0 = threadIdx.x >> 6;
    #pragma unroll
    for (int nn = wn0; nn < 64; nn += 4)
        ob[(size_t)(n0 + nn) * ldo + k0 + wk] = f2b(tile[wk][nn]);
}

// ---------------------------------------------------------------------------
// MFMA bf16 GEMM, 128x128 tile, BK=32, 256 thr (4 waves 2x2), m97 structure.
// A: [M][lda] bf16 row-major.  B: [N][ldb] bf16 N-MAJOR (row n = output col).
// grid: (N/128, M/128, Z) — Z>1 = split-K (global k = z*K + kb), EPI 3 only.
// EPI 0: qkv — dst/bias selected by col block: C0/C1/C2, bias/auxb1/auxb2
// EPI 1: C0[r*ldc+c] += acc + (bias?bias[c]:0)       (bf16 rmw)
// EPI 2: C0[r*ldc+c]  = gelu_erf(acc + bias[c])
// EPI 3: atomicAdd(fout[((r>>5)*512+c)*32 + (r&31)], acc*stdev[r])
// ---------------------------------------------------------------------------
template<int EPI>
__global__ __launch_bounds__(256) void mfma_gemm(
    const u16* __restrict__ A, const u16* __restrict__ B,
    const float* __restrict__ bias, const float* __restrict__ auxb1,
    const float* __restrict__ auxb2,
    u16* __restrict__ C0, u16* __restrict__ C1, u16* __restrict__ C2,
    float* __restrict__ fout, const float* __restrict__ stdev,
    int K, int lda, int ldb, int ldc)
{
    __shared__ u16 As[128 * 32];
    __shared__ u16 Bs[128 * 32];
    const int tid = threadIdx.x;
    const int lane = tid & 63;
    const int wave = tid >> 6;
    const int row0 = blockIdx.y * 128;
    const int col0 = blockIdx.x * 128;
    const size_t zoff = (size_t)blockIdx.z * K;

    const int stRow = (wave << 4) + (lane >> 2);
    const int stCol = (lane & 3) << 3;
    const u16* Ag = A + (size_t)(row0 + stRow) * lda + zoff + stCol;
    const u16* Bg = B + (size_t)(col0 + stRow) * ldb + zoff + stCol;
    u16* AsW = As + (wave << 4) * 32;
    u16* BsW = Bs + (wave << 4) * 32;

    const int fm = lane & 15;
    const int fk = (lane >> 4) << 3;
    const int wm = wave & 1, wn = wave >> 1;

    f32x4 acc[4][4];
    #pragma unroll
    for (int i = 0; i < 4; i++)
        #pragma unroll
        for (int j = 0; j < 4; j++)
            acc[i][j] = (f32x4){0.f, 0.f, 0.f, 0.f};

    for (int kb = 0; kb < K; kb += 32) {
        __syncthreads();
        async_copy16(Ag + kb, AsW);
        async_copy16(Ag + kb + (size_t)64 * lda, AsW + 64 * 32);
        async_copy16(Bg + kb, BsW);
        async_copy16(Bg + kb + (size_t)64 * ldb, BsW + 64 * 32);
        __syncthreads();
        short8 af[4], bfr[4];
        #pragma unroll
        for (int mi = 0; mi < 4; mi++)
            af[mi] = *(const short8*)&As[((wm << 6) + (mi << 4) + fm) * 32 + fk];
        #pragma unroll
        for (int ni = 0; ni < 4; ni++)
            bfr[ni] = *(const short8*)&Bs[((wn << 6) + (ni << 4) + fm) * 32 + fk];
        #pragma unroll
        for (int mi = 0; mi < 4; mi++)
            #pragma unroll
            for (int ni = 0; ni < 4; ni++)
                acc[mi][ni] = __builtin_amdgcn_mfma_f32_16x16x32_bf16(
                    af[mi], bfr[ni], acc[mi][ni], 0, 0, 0);
    }

    // epilogue: C/D layout col=lane&15, row=(lane>>4)*4+i  [m89-verified]
    const int er = (lane >> 4) << 2;
    const int ec = lane & 15;
    u16* dsel = C0;
    const float* bsel = bias;
    if (EPI == 0) {
        int sub = col0 >> 9;
        dsel = (sub == 0) ? C0 : ((sub == 1) ? C1 : C2);
        bsel = (sub == 0) ? bias : ((sub == 1) ? auxb1 : auxb2);
    }
    #pragma unroll
    for (int mi = 0; mi < 4; mi++) {
        #pragma unroll
        for (int ni = 0; ni < 4; ni++) {
            #pragma unroll
            for (int i = 0; i < 4; i++) {
                int r = row0 + (wm << 6) + (mi << 4) + er + i;
                int cc = col0 + (wn << 6) + (ni << 4) + ec;
                float v = acc[mi][ni][i];
                if (EPI == 0) {
                    int cl = cc & 511;
                    dsel[(size_t)r * 512 + cl] = f2b(v + bsel[cl]);
                } else if (EPI == 1) {
                    size_t o = (size_t)r * ldc + cc;
                    float bb = bias ? bias[cc] : 0.f;
                    C0[o] = f2b(b2f(C0[o]) + v + bb);
                } else if (EPI == 2) {
                    size_t o = (size_t)r * ldc + cc;
                    float z = v + bias[cc];
                    C0[o] = f2b(0.5f * z * (1.f + erff(z * 0.7071067811865475f)));
                } else {
                    float vv = v * stdev[r];
                    atomicAdd(&fout[(((size_t)(r >> 5) * kT + cc) << 5) + (r & 31)], vv);
                }
            }
        }
    }
}

// ---------------------------------------------------------------------------
// MFMA attention. One block per series; 4 waves; wave w does heads 2w, 2w+1.
// q,k,v: bf16 [rows=64*series][512]; output in place over q (wave w owns
// q columns [128w,128w+128) — disjoint across waves).
// QK^T and PV via mfma_f32_16x16x32_bf16; P converts C->A layout via LDS.
// ---------------------------------------------------------------------------
__global__ __launch_bounds__(256) void attn_mfma_kernel(
    u16* __restrict__ qbuf, const u16* __restrict__ kbuf,
    const u16* __restrict__ vbuf)
{
    __shared__ u16 P[4][64 * 64];   // 8 KB per wave
    const int tid = threadIdx.x;
    const int wave = tid >> 6, lane = tid & 63;
    const int quad = lane >> 4, l15 = lane & 15;
    const size_t base = (size_t)blockIdx.x * 64 * kD;
    u16* Pw = P[wave];

    for (int hh = 0; hh < 2; hh++) {
        const int h = wave * 2 + hh;
        const u16* qh = qbuf + base + h * 64;
        const u16* kh = kbuf + base + h * 64;
        const u16* vh = vbuf + base + h * 64;

        // Q as A-operand, K as B-operand: contiguous 16B per lane
        short8 af[4][2], bf[4][2];
        #pragma unroll
        for (int mi = 0; mi < 4; mi++)
            #pragma unroll
            for (int kt = 0; kt < 2; kt++)
                af[mi][kt] = *(const short8*)(qh + (size_t)(mi * 16 + l15) * kD
                                              + kt * 32 + quad * 8);
        #pragma unroll
        for (int ni = 0; ni < 4; ni++)
            #pragma unroll
            for (int kt = 0; kt < 2; kt++)
                bf[ni][kt] = *(const short8*)(kh + (size_t)(ni * 16 + l15) * kD
                                              + kt * 32 + quad * 8);
        f32x4 S[4][4];
        #pragma unroll
        for (int mi = 0; mi < 4; mi++)
            #pragma unroll
            for (int ni = 0; ni < 4; ni++)
                S[mi][ni] = (f32x4){0.f, 0.f, 0.f, 0.f};
        #pragma unroll
        for (int mi = 0; mi < 4; mi++)
            #pragma unroll
            for (int ni = 0; ni < 4; ni++) {
                S[mi][ni] = __builtin_amdgcn_mfma_f32_16x16x32_bf16(
                    af[mi][0], bf[ni][0], S[mi][ni], 0, 0, 0);
                S[mi][ni] = __builtin_amdgcn_mfma_f32_16x16x32_bf16(
                    af[mi][1], bf[ni][1], S[mi][ni], 0, 0, 0);
            }

        // softmax over each row (row = mi*16 + quad*4 + i spans 16 lanes x 4 ni)
        #pragma unroll
        for (int mi = 0; mi < 4; mi++) {
            #pragma unroll
            for (int i = 0; i < 4; i++) {
                float mx = -1e30f;
                #pragma unroll
                for (int ni = 0; ni < 4; ni++) {
                    float v = S[mi][ni][i] * 0.125f;
                    S[mi][ni][i] = v;
                    mx = fmaxf(mx, v);
                }
                #pragma unroll
                for (int off = 1; off < 16; off <<= 1)
                    mx = fmaxf(mx, __shfl_xor(mx, off));
                float sum = 0.f;
                #pragma unroll
                for (int ni = 0; ni < 4; ni++) {
                    float e = expf(S[mi][ni][i] - mx);
                    S[mi][ni][i] = e;
                    sum += e;
                }
                #pragma unroll
                for (int off = 1; off < 16; off <<= 1)
                    sum += __shfl_xor(sum, off);
                float inv = 1.f / sum;
                #pragma unroll
                for (int ni = 0; ni < 4; ni++)
                    Pw[(mi * 16 + quad * 4 + i) * 64 + ni * 16 + l15] =
                        f2b(S[mi][ni][i] * inv);
            }
        }
        __syncthreads();   // P writes drained (compiler waits lgkmcnt pre-barrier)

        // V as B-operand: B[n=e][k=s] = v[s][e] — strided 2B gathers (L2-hot)
        short8 bv[4][2];
        #pragma unroll
        for (int ni = 0; ni < 4; ni++)
            #pragma unroll
            for (int kt = 0; kt < 2; kt++)
                #pragma unroll
                for (int j = 0; j < 8; j++)
                    bv[ni][kt][j] = (short)vh[(size_t)(kt * 32 + quad * 8 + j) * kD
                                              + ni * 16 + l15];
        // P as A-operand from LDS: contiguous 16B per lane
        short8 pa[4][2];
        #pragma unroll
        for (int mi = 0; mi < 4; mi++)
            #pragma unroll
            for (int kt = 0; kt < 2; kt++)
                pa[mi][kt] = *(const short8*)&Pw[(mi * 16 + l15) * 64
                                                 + kt * 32 + quad * 8];
        f32x4 O[4][4];
        #pragma unroll
        for (int mi = 0; mi < 4; mi++)
            #pragma unroll
            for (int ni = 0; ni < 4; ni++)
                O[mi][ni] = (f32x4){0.f, 0.f, 0.f, 0.f};
        #pragma unroll
        for (int mi = 0; mi < 4; mi++)
            #pragma unroll
            for (int ni = 0; ni < 4; ni++) {
                O[mi][ni] = __builtin_amdgcn_mfma_f32_16x16x32_bf16(
                    pa[mi][0], bv[ni][0], O[mi][ni], 0, 0, 0);
                O[mi][ni] = __builtin_amdgcn_mfma_f32_16x16x32_bf16(
                    pa[mi][1], bv[ni][1], O[mi][ni], 0, 0, 0);
            }
        // write attn-out over q (C layout: row=quad*4+i, col=l15)
        u16* qo = qbuf + base + h * 64;
        #pragma unroll
        for (int mi = 0; mi < 4; mi++)
            #pragma unroll
            for (int ni = 0; ni < 4; ni++)
                #pragma unroll
                for (int i = 0; i < 4; i++)
                    qo[(size_t)(mi * 16 + quad * 4 + i) * kD + ni * 16 + l15] =
                        f2b(O[mi][ni][i]);
        __syncthreads();   // before P overwrite next iteration
    }
}

// ---------------------------------------------------------------------------
// Row LayerNorm over D=512, bf16 in/out, in-place safe. 4 rows per block
// (one wave each).  grid: rows/4.
// ---------------------------------------------------------------------------
__global__ __launch_bounds__(256) void ln_kernel(
    const u16* __restrict__ x, const float* __restrict__ g,
    const float* __restrict__ bb, u16* __restrict__ y)
{
    size_t row = (size_t)blockIdx.x * 4 + (threadIdx.x >> 6);
    int lane = threadIdx.x & 63;
    float v[8];
    float s = 0.f;
    #pragma unroll
    for (int i = 0; i < 8; i++) {
        v[i] = b2f(x[row * kD + lane + i * 64]);
        s += v[i];
    }
    #pragma unroll
    for (int off = 32; off; off >>= 1) s += __shfl_xor(s, off);
    float mean = s * (1.f / kD);
    float sq = 0.f;
    #pragma unroll
    for (int i = 0; i < 8; i++) { float d = v[i] - mean; sq += d * d; }
    #pragma unroll
    for (int off = 32; off; off >>= 1) sq += __shfl_xor(sq, off);
    float inv = 1.f / sqrtf(sq * (1.f / kD) + 1e-5f);
    #pragma unroll
    for (int i = 0; i < 8; i++) {
        int d = lane + i * 64;
        y[row * kD + d] = f2b((v[i] - mean) * inv * g[d] + bb[d]);
    }
}

// ---------------------------------------------------------------------------
// BatchNorm pieces
// ---------------------------------------------------------------------------
__global__ void zero_kernel(float* __restrict__ p, int n)
{
    int i = blockIdx.x * blockDim.x + threadIdx.x;
    if (i < n) p[i] = 0.f;
}

__global__ __launch_bounds__(512) void bn_stats_kernel(
    const u16* __restrict__ tok, float* __restrict__ sums, float* __restrict__ sumsq)
{
    int d = threadIdx.x;
    float s = 0.f, sq = 0.f;
    int row0 = blockIdx.x * 256;
    for (int row = row0; row < row0 + 256; row++) {
        float v = b2f(tok[(size_t)row * kD + d]);
        s += v; sq += v * v;
    }
    atomicAdd(&sums[d], s);
    atomicAdd(&sumsq[d], sq);
}

__global__ __launch_bounds__(512) void bn_final_kernel(
    const float* __restrict__ sums, const float* __restrict__ sumsq,
    const float* __restrict__ g, const float* __restrict__ bb,
    float* __restrict__ scale, float* __restrict__ shift)
{
    int d = threadIdx.x;
    float mean = sums[d] / (float)kM;
    float var = sumsq[d] / (float)kM - mean * mean;
    float sc = g[d] / sqrtf(var + 1e-5f);
    scale[d] = sc;
    shift[d] = bb[d] - mean * sc;
}

// in-place BN on tok (bf16)
__global__ __launch_bounds__(256) void bn_apply_kernel(
    u16* __restrict__ tok, const float* __restrict__ scale,
    const float* __restrict__ shift)
{
    size_t i = (size_t)blockIdx.x * 256 + threadIdx.x;
    int d = (int)(i & 511);
    tok[i] = f2b(b2f(tok[i]) * scale[d] + shift[d]);
}

// out[(b*T+t)*C+c] = b_head[t]*stdev[r]+means[r]  (split-K partials add onto it)
__global__ __launch_bounds__(256) void head_init_kernel(
    float* __restrict__ out, const float* __restrict__ b_head,
    const float* __restrict__ stdev, const float* __restrict__ means)
{
    int i = blockIdx.x * 256 + threadIdx.x;
    int c = i & 31, t = (i >> 5) & 511, b = i >> 14;
    int r = b * 32 + c;
    out[i] = b_head[t] * stdev[r] + means[r];
}

// ---------------------------------------------------------------------------
// Launch
// ---------------------------------------------------------------------------
extern "C" void kernel_launch(void* const* d_in, const int* in_sizes, int n_in,
                              void* d_out, int out_size, void* d_ws, size_t ws_size,
                              hipStream_t stream)
{
    const float* x_enc  = (const float*)d_in[0];
    const float* W_val  = (const float*)d_in[1];
    const float* Wq     = (const float*)d_in[2];
    const float* bq     = (const float*)d_in[3];
    const float* Wk     = (const float*)d_in[4];
    const float* bk     = (const float*)d_in[5];
    const float* Wv     = (const float*)d_in[6];
    const float* bv     = (const float*)d_in[7];
    const float* Wo     = (const float*)d_in[8];
    const float* bo     = (const float*)d_in[9];
    const float* Wc1    = (const float*)d_in[10];
    const float* bc1    = (const float*)d_in[11];
    const float* Wc2    = (const float*)d_in[12];
    const float* bc2    = (const float*)d_in[13];
    const float* ln1_g  = (const float*)d_in[14];
    const float* ln1_b  = (const float*)d_in[15];
    const float* ln2_g  = (const float*)d_in[16];
    const float* ln2_b  = (const float*)d_in[17];
    const float* bn_g   = (const float*)d_in[18];
    const float* bn_b   = (const float*)d_in[19];
    const float* W_head = (const float*)d_in[20];
    const float* b_head = (const float*)d_in[21];
    float* out = (float*)d_out;

    // --- adaptive chunk size: largest CH with tok + 3 units + weights fitting
    const size_t tailBytes = (2 * kR + 4 * kD) * sizeof(float);
    const size_t headWb = (size_t)512 * 32768;   // W_head bf16 overlay elems
    int CH = 0; size_t unit = 0, region = 0;
    const int cands[4] = {1024, 512, 256, 128};
    for (int ci = 0; ci < 4; ci++) {
        size_t u = (size_t)cands[ci] * 64 * kD;
        size_t reg = 3 * u + kWbElems;
        if (reg < headWb) reg = headWb;
        size_t need = ((size_t)kM * kD + reg) * 2 + tailBytes;
        if (need <= ws_size) { CH = cands[ci]; unit = u; region = reg; break; }
    }
    if (CH == 0) {
        hipLaunchKernelGGL(fill_kernel, dim3((out_size + 255) / 256), dim3(256), 0,
                           stream, out, 1.0e6f, out_size);
        return;
    }
    const int nch = kR / CH;
    const int chRows = CH * 64;

    u16* tokb = (u16*)d_ws;
    u16* s0  = tokb + (size_t)kM * kD;
    u16* s1  = s0 + unit;
    u16* s2  = s1 + unit;
    u16* wbL = s2 + unit;
    u16* wbH = s0;
    u16* wQKV = wbL;                       // [1536][512]
    u16* wO   = wQKV + (size_t)1536 * 512; // [512][512]
    u16* wC1  = wO + (size_t)512 * 512;    // [2048][512]
    u16* wC2  = wC1 + (size_t)2048 * 512;  // [512][2048]
    float* tail = (float*)(s0 + region);
    float* means    = tail;
    float* stdevp   = means + kR;
    float* bn_sums  = stdevp + kR;
    float* bn_sumsq = bn_sums + kD;
    float* bn_scale = bn_sumsq + kD;
    float* bn_shift = bn_scale + kD;

    hipLaunchKernelGGL(instnorm_stats_kernel, dim3(kB), dim3(256), 0, stream,
                       x_enc, means, stdevp);
    hipLaunchKernelGGL(patch_embed_kernel, dim3(kM), dim3(256), 0, stream,
                       x_enc, W_val, means, stdevp, tokb);

    const dim3 blk(256);
    const dim3 tr8(8, 8, 1);
    const int mt = chRows / 128;   // M tiles per chunk

    for (int i = 0; i < kNL; i++) {
        const float* Wq_i = Wq + (size_t)i * kD * kD;
        const float* Wk_i = Wk + (size_t)i * kD * kD;
        const float* Wv_i = Wv + (size_t)i * kD * kD;
        const float* Wo_i = Wo + (size_t)i * kD * kD;
        const float* Wc1_i = Wc1 + (size_t)i * kD * kDFF;
        const float* Wc2_i = Wc2 + (size_t)i * kDFF * kD;
        const float* bq_i = bq + i * kD, *bk_i = bk + i * kD, *bv_i = bv + i * kD;

        hipLaunchKernelGGL(transpose_cvt_kernel, tr8, blk, 0, stream,
                           Wq_i, wQKV, kD, kD, 0, 0);
        hipLaunchKernelGGL(transpose_cvt_kernel, tr8, blk, 0, stream,
                           Wk_i, wQKV + (size_t)512 * 512, kD, kD, 0, 0);
        hipLaunchKernelGGL(transpose_cvt_kernel, tr8, blk, 0, stream,
                           Wv_i, wQKV + (size_t)1024 * 512, kD, kD, 0, 0);
        hipLaunchKernelGGL(transpose_cvt_kernel, tr8, blk, 0, stream,
                           Wo_i, wO, kD, kD, 0, 0);
        hipLaunchKernelGGL(transpose_cvt_kernel, dim3(8, 32, 1), blk, 0, stream,
                           Wc1_i, wC1, kDFF, kD, 0, 0);
        hipLaunchKernelGGL(transpose_cvt_kernel, dim3(32, 8, 1), blk, 0, stream,
                           Wc2_i, wC2, kD, kDFF, 0, 0);

        for (int ch = 0; ch < nch; ch++) {
            u16* tokc = tokb + (size_t)ch * chRows * kD;
            // fused QKV: N=1536, routed to s0/s1/s2
            hipLaunchKernelGGL(mfma_gemm<0>, dim3(12, mt, 1), blk, 0, stream,
                               tokc, wQKV, bq_i, bk_i, bv_i, s0, s1, s2,
                               nullptr, nullptr, kD, kD, kD, kD);
            hipLaunchKernelGGL(attn_mfma_kernel, dim3(CH), blk, 0, stream,
                               s0, s1, s2);
            // tok += attn_out @ Wo + bo
            hipLaunchKernelGGL(mfma_gemm<1>, dim3(4, mt, 1), blk, 0, stream,
                               s0, wO, bo + i * kD, nullptr, nullptr,
                               tokc, nullptr, nullptr, nullptr, nullptr,
                               kD, kD, kD, kD);
            // y = LN1(tok) -> s0
            hipLaunchKernelGGL(ln_kernel, dim3(chRows / 4), blk, 0, stream,
                               tokc, ln1_g + i * kD, ln1_b + i * kD, s0);
            // FFN in two DFF/2 halves; h lives in s1:s2 (2 units)
            for (int half = 0; half < 2; half++) {
                const u16* wc1h = wC1 + (size_t)half * 1024 * 512;
                const u16* wc2h = wC2 + (size_t)half * 1024;   // k-offset
                const float* bc1h = bc1 + (size_t)i * kDFF + half * 1024;
                hipLaunchKernelGGL(mfma_gemm<2>, dim3(8, mt, 1), blk, 0, stream,
                                   s0, wc1h, bc1h, nullptr, nullptr,
                                   s1, nullptr, nullptr, nullptr, nullptr,
                                   kD, kD, kD, 1024);
                hipLaunchKernelGGL(mfma_gemm<1>, dim3(4, mt, 1), blk, 0, stream,
                                   s1, wc2h, (half == 0) ? (bc2 + i * kD) : nullptr,
                                   nullptr, nullptr, tokc, nullptr, nullptr,
                                   nullptr, nullptr, 1024, 1024, kDFF, kD);
            }
            // tok = LN2(tok) in place
            hipLaunchKernelGGL(ln_kernel, dim3(chRows / 4), blk, 0, stream,
                               tokc, ln2_g + i * kD, ln2_b + i * kD, tokc);
        }
    }

    // BatchNorm (stats -> apply in place on tok)
    hipLaunchKernelGGL(zero_kernel, dim3(1), dim3(1024), 0, stream, bn_sums, 2 * kD);
    hipLaunchKernelGGL(bn_stats_kernel, dim3(kM / 256), dim3(512), 0, stream,
                       tokb, bn_sums, bn_sumsq);
    hipLaunchKernelGGL(bn_final_kernel, dim3(1), dim3(512), 0, stream,
                       bn_sums, bn_sumsq, bn_g, bn_b, bn_scale, bn_shift);
    hipLaunchKernelGGL(bn_apply_kernel, dim3((int)((size_t)kM * kD / 256)), blk, 0,
                       stream, tokb, bn_scale, bn_shift);

    // head weights: wbH[t][n*512+d] = W_head[(d*64+n)*512+t]  (k' = n*512+d)
    hipLaunchKernelGGL(transpose_cvt_kernel, dim3(8, 8, 64), blk, 0, stream,
                       W_head, wbH, 64 * 512, 32768, 512, 512);
    // out = b_head*stdev+mean, then split-K MFMA adds acc*stdev
    hipLaunchKernelGGL(head_init_kernel, dim3(out_size / 256), blk, 0, stream,
                       out, b_head, stdevp, means);
    // A = tok viewed as [1024][32768] (k'=n*512+d is the flat tok order)
    hipLaunchKernelGGL(mfma_gemm<3>, dim3(4, 8, 8), blk, 0, stream,
                       tokb, wbH, nullptr, nullptr, nullptr,
                       nullptr, nullptr, nullptr, out, stdevp,
                       4096, 32768, 32768, kT);
}

// Round 5
// 3803.739 us; speedup vs baseline: 6.2745x; 1.0199x over previous
//
#include <hip/hip_runtime.h>
#include <math.h>

// ---------------------------------------------------------------------------
// Problem constants (PatchTST-style transformer)
// ---------------------------------------------------------------------------
namespace {
constexpr int kB = 32, kT = 512, kC = 32, kD = 512, kDFF = 2048, kNL = 3;
constexpr int kP = 16, kStride = 8, kN = 64;
constexpr int kR = kB * kC;      // 1024 independent (b,c) series
constexpr int kM = kR * kN;      // 65536 tokens total
constexpr size_t kWbElems = (size_t)1536 * 512 + 512 * 512 + 2048 * 512 + 512 * 2048;
}

typedef unsigned short u16;
typedef __attribute__((ext_vector_type(8))) short short8;   // 8 bf16 (4 VGPRs)
typedef __attribute__((ext_vector_type(4))) float f32x4;    // MFMA accumulator

__device__ __forceinline__ float b2f(u16 u) {
    return __uint_as_float(((unsigned int)u) << 16);
}
__device__ __forceinline__ u16 f2b(float f) {
    unsigned int x = __float_as_uint(f);
    return (u16)((x + 0x7fffu + ((x >> 16) & 1u)) >> 16);
}

// async global->LDS, 16B per lane. lds ptr must be wave-uniform base.
__device__ __forceinline__ void async_copy16(const void* g, void* l) {
    __builtin_amdgcn_global_load_lds(
        (const __attribute__((address_space(1))) unsigned int*)g,
        (__attribute__((address_space(3))) unsigned int*)l, 16, 0, 0);
}

// ---------------------------------------------------------------------------
// Sentinel fill (workspace-too-small diagnostic)
// ---------------------------------------------------------------------------
__global__ void fill_kernel(float* __restrict__ p, float val, int n)
{
    int i = blockIdx.x * blockDim.x + threadIdx.x;
    if (i < n) p[i] = val;
}

// ---------------------------------------------------------------------------
// Instance-norm stats per (b,c)
// ---------------------------------------------------------------------------
__global__ __launch_bounds__(256) void instnorm_stats_kernel(
    const float* __restrict__ x, float* __restrict__ means, float* __restrict__ stdev)
{
    int b = blockIdx.x;
    int c = threadIdx.x & 31;
    int g = threadIdx.x >> 5;
    float s = 0.f, sq = 0.f;
    for (int t = g; t < kT; t += 8) {
        float v = x[(size_t)(b * kT + t) * kC + c];
        s += v; sq += v * v;
    }
    __shared__ float ss[8][32], ssq[8][32];
    ss[g][c] = s; ssq[g][c] = sq;
    __syncthreads();
    if (g == 0) {
        float S = 0.f, SQ = 0.f;
        for (int i = 0; i < 8; i++) { S += ss[i][c]; SQ += ssq[i][c]; }
        float m = S / kT;
        float var = SQ / kT - m * m;
        means[b * kC + c] = m;
        stdev[b * kC + c] = sqrtf(var + 1e-5f);
    }
}

// ---------------------------------------------------------------------------
// Patch embed (bf16 out)
// ---------------------------------------------------------------------------
__global__ __launch_bounds__(256) void patch_embed_kernel(
    const float* __restrict__ x, const float* __restrict__ Wval,
    const float* __restrict__ means, const float* __restrict__ stdev,
    u16* __restrict__ tok)
{
    int m = blockIdx.x;
    int r = m >> 6, n = m & 63;
    int b = r >> 5, c = r & 31;
    __shared__ float patch[kP];
    if (threadIdx.x < kP) {
        int t = n * kStride + threadIdx.x;
        if (t > kT - 1) t = kT - 1;
        patch[threadIdx.x] = (x[(size_t)(b * kT + t) * kC + c] - means[r]) / stdev[r];
    }
    __syncthreads();
    for (int d = threadIdx.x; d < kD; d += 256) {
        float acc = 0.f;
        #pragma unroll
        for (int p = 0; p < kP; p++) acc += patch[p] * Wval[p * kD + d];
        int j = d >> 1;
        float freq = expf(-(float)(2 * j) * (9.210340371976184f / (float)kD));
        float ang = (float)n * freq;
        float pe = (d & 1) ? cosf(ang) : sinf(ang);
        tok[(size_t)m * kD + d] = f2b(acc + pe);
    }
}

// ---------------------------------------------------------------------------
// Transpose + fp32->bf16 convert: out[n*ldo + k] = f2b(in[k*ldi + n])
// per z-slice: in += z*zin, out += z*zout.  grid (K/64, N/64, Z), 256 thr.
// ---------------------------------------------------------------------------
__global__ __launch_bounds__(256) void transpose_cvt_kernel(
    const float* __restrict__ in, u16* __restrict__ outp,
    int ldi, int ldo, int zin, int zout)
{
    __shared__ float tile[64][65];
    const float* ib = in + (size_t)blockIdx.z * zin;
    u16* ob = outp + (size_t)blockIdx.z * zout;
    int k0 = blockIdx.x * 64, n0 = blockIdx.y * 64;
    int tn = threadIdx.x & 63, tk0 = threadIdx.x >> 6;
    #pragma unroll
    for (int kk = tk0; kk < 64; kk += 4)
        tile[kk][tn] = ib[(size_t)(k0 + kk) * ldi + n0 + tn];
    __syncthreads();
    int wk = threadIdx.x & 63, wn0 = threadIdx.x >> 6;
    #pragma unroll
    for (int nn = wn0; nn < 64; nn += 4)
        ob[(size_t)(n0 + nn) * ldo + k0 + wk] = f2b(tile[wk][nn]);
}

// ---------------------------------------------------------------------------
// MFMA bf16 GEMM, 128x128 tile, BK=32, 256 thr (4 waves 2x2), m97 structure.
// LDS chunk-XOR swizzle: physical 16B chunk p of row r holds logical chunk
// p ^ (r&3). Staging permutes the GLOBAL source chunk per lane (LDS dest of
// global_load_lds is fixed at base+lane*16); fragment reads apply inverse
// XOR. Breaks the 8-way bank aliasing of 64B-strided rows (R4: 4.19M
// SQ_LDS_BANK_CONFLICT -> ~0, consecutive lanes now hit 4 distinct windows).
// A: [M][lda] bf16 row-major.  B: [N][ldb] bf16 N-MAJOR (row n = output col).
// grid: (N/128, M/128, Z) — Z>1 = split-K (global k = z*K + kb), EPI 3 only.
// EPI 0: qkv — dst/bias selected by col block: C0/C1/C2, bias/auxb1/auxb2
// EPI 1: C0[r*ldc+c] += acc + (bias?bias[c]:0)       (bf16 rmw)
// EPI 2: C0[r*ldc+c]  = gelu_erf(acc + bias[c])
// EPI 3: atomicAdd(fout[((r>>5)*512+c)*32 + (r&31)], acc*stdev[r])
// ---------------------------------------------------------------------------
template<int EPI>
__global__ __launch_bounds__(256) void mfma_gemm(
    const u16* __restrict__ A, const u16* __restrict__ B,
    const float* __restrict__ bias, const float* __restrict__ auxb1,
    const float* __restrict__ auxb2,
    u16* __restrict__ C0, u16* __restrict__ C1, u16* __restrict__ C2,
    float* __restrict__ fout, const float* __restrict__ stdev,
    int K, int lda, int ldb, int ldc)
{
    __shared__ u16 As[128 * 32];
    __shared__ u16 Bs[128 * 32];
    const int tid = threadIdx.x;
    const int lane = tid & 63;
    const int wave = tid >> 6;
    const int row0 = blockIdx.y * 128;
    const int col0 = blockIdx.x * 128;
    const size_t zoff = (size_t)blockIdx.z * K;

    const int stRow = (wave << 4) + (lane >> 2);
    // swizzle: this lane's LDS slot is physical chunk (lane&3) of row stRow;
    // it must stage logical chunk (lane&3) ^ (stRow&3) = (lane&3)^((lane>>2)&3)
    const int stCol = ((lane & 3) ^ ((lane >> 2) & 3)) << 3;
    const u16* Ag = A + (size_t)(row0 + stRow) * lda + zoff + stCol;
    const u16* Bg = B + (size_t)(col0 + stRow) * ldb + zoff + stCol;
    u16* AsW = As + (wave << 4) * 32;
    u16* BsW = Bs + (wave << 4) * 32;

    const int fm = lane & 15;
    // logical chunk kt = lane>>4 at row lr (lr&3 == lane&3) sits at physical
    // chunk kt ^ (lr&3)  ->  lane-constant offset:
    const int fkx = ((lane >> 4) ^ (lane & 3)) << 3;
    const int wm = wave & 1, wn = wave >> 1;

    f32x4 acc[4][4];
    #pragma unroll
    for (int i = 0; i < 4; i++)
        #pragma unroll
        for (int j = 0; j < 4; j++)
            acc[i][j] = (f32x4){0.f, 0.f, 0.f, 0.f};

    for (int kb = 0; kb < K; kb += 32) {
        __syncthreads();
        async_copy16(Ag + kb, AsW);
        async_copy16(Ag + kb + (size_t)64 * lda, AsW + 64 * 32);
        async_copy16(Bg + kb, BsW);
        async_copy16(Bg + kb + (size_t)64 * ldb, BsW + 64 * 32);
        __syncthreads();
        short8 af[4], bfr[4];
        #pragma unroll
        for (int mi = 0; mi < 4; mi++)
            af[mi] = *(const short8*)&As[((wm << 6) + (mi << 4) + fm) * 32 + fkx];
        #pragma unroll
        for (int ni = 0; ni < 4; ni++)
            bfr[ni] = *(const short8*)&Bs[((wn << 6) + (ni << 4) + fm) * 32 + fkx];
        #pragma unroll
        for (int mi = 0; mi < 4; mi++)
            #pragma unroll
            for (int ni = 0; ni < 4; ni++)
                acc[mi][ni] = __builtin_amdgcn_mfma_f32_16x16x32_bf16(
                    af[mi], bfr[ni], acc[mi][ni], 0, 0, 0);
    }

    // epilogue: C/D layout col=lane&15, row=(lane>>4)*4+i  [m89-verified]
    const int er = (lane >> 4) << 2;
    const int ec = lane & 15;
    u16* dsel = C0;
    const float* bsel = bias;
    if (EPI == 0) {
        int sub = col0 >> 9;
        dsel = (sub == 0) ? C0 : ((sub == 1) ? C1 : C2);
        bsel = (sub == 0) ? bias : ((sub == 1) ? auxb1 : auxb2);
    }
    #pragma unroll
    for (int mi = 0; mi < 4; mi++) {
        #pragma unroll
        for (int ni = 0; ni < 4; ni++) {
            #pragma unroll
            for (int i = 0; i < 4; i++) {
                int r = row0 + (wm << 6) + (mi << 4) + er + i;
                int cc = col0 + (wn << 6) + (ni << 4) + ec;
                float v = acc[mi][ni][i];
                if (EPI == 0) {
                    int cl = cc & 511;
                    dsel[(size_t)r * 512 + cl] = f2b(v + bsel[cl]);
                } else if (EPI == 1) {
                    size_t o = (size_t)r * ldc + cc;
                    float bb = bias ? bias[cc] : 0.f;
                    C0[o] = f2b(b2f(C0[o]) + v + bb);
                } else if (EPI == 2) {
                    size_t o = (size_t)r * ldc + cc;
                    float z = v + bias[cc];
                    C0[o] = f2b(0.5f * z * (1.f + erff(z * 0.7071067811865475f)));
                } else {
                    float vv = v * stdev[r];
                    atomicAdd(&fout[(((size_t)(r >> 5) * kT + cc) << 5) + (r & 31)], vv);
                }
            }
        }
    }
}

// ---------------------------------------------------------------------------
// MFMA attention. One block per series; 4 waves; wave w does heads 2w, 2w+1.
// q,k,v: bf16 [rows=64*series][512]; output in place over q.
// ---------------------------------------------------------------------------
__global__ __launch_bounds__(256) void attn_mfma_kernel(
    u16* __restrict__ qbuf, const u16* __restrict__ kbuf,
    const u16* __restrict__ vbuf)
{
    __shared__ u16 P[4][64 * 64];   // 8 KB per wave
    const int tid = threadIdx.x;
    const int wave = tid >> 6, lane = tid & 63;
    const int quad = lane >> 4, l15 = lane & 15;
    const size_t base = (size_t)blockIdx.x * 64 * kD;
    u16* Pw = P[wave];

    for (int hh = 0; hh < 2; hh++) {
        const int h = wave * 2 + hh;
        const u16* qh = qbuf + base + h * 64;
        const u16* kh = kbuf + base + h * 64;
        const u16* vh = vbuf + base + h * 64;

        short8 af[4][2], bf[4][2];
        #pragma unroll
        for (int mi = 0; mi < 4; mi++)
            #pragma unroll
            for (int kt = 0; kt < 2; kt++)
                af[mi][kt] = *(const short8*)(qh + (size_t)(mi * 16 + l15) * kD
                                              + kt * 32 + quad * 8);
        #pragma unroll
        for (int ni = 0; ni < 4; ni++)
            #pragma unroll
            for (int kt = 0; kt < 2; kt++)
                bf[ni][kt] = *(const short8*)(kh + (size_t)(ni * 16 + l15) * kD
                                              + kt * 32 + quad * 8);
        f32x4 S[4][4];
        #pragma unroll
        for (int mi = 0; mi < 4; mi++)
            #pragma unroll
            for (int ni = 0; ni < 4; ni++)
                S[mi][ni] = (f32x4){0.f, 0.f, 0.f, 0.f};
        #pragma unroll
        for (int mi = 0; mi < 4; mi++)
            #pragma unroll
            for (int ni = 0; ni < 4; ni++) {
                S[mi][ni] = __builtin_amdgcn_mfma_f32_16x16x32_bf16(
                    af[mi][0], bf[ni][0], S[mi][ni], 0, 0, 0);
                S[mi][ni] = __builtin_amdgcn_mfma_f32_16x16x32_bf16(
                    af[mi][1], bf[ni][1], S[mi][ni], 0, 0, 0);
            }

        #pragma unroll
        for (int mi = 0; mi < 4; mi++) {
            #pragma unroll
            for (int i = 0; i < 4; i++) {
                float mx = -1e30f;
                #pragma unroll
                for (int ni = 0; ni < 4; ni++) {
                    float v = S[mi][ni][i] * 0.125f;
                    S[mi][ni][i] = v;
                    mx = fmaxf(mx, v);
                }
                #pragma unroll
                for (int off = 1; off < 16; off <<= 1)
                    mx = fmaxf(mx, __shfl_xor(mx, off));
                float sum = 0.f;
                #pragma unroll
                for (int ni = 0; ni < 4; ni++) {
                    float e = expf(S[mi][ni][i] - mx);
                    S[mi][ni][i] = e;
                    sum += e;
                }
                #pragma unroll
                for (int off = 1; off < 16; off <<= 1)
                    sum += __shfl_xor(sum, off);
                float inv = 1.f / sum;
                #pragma unroll
                for (int ni = 0; ni < 4; ni++)
                    Pw[(mi * 16 + quad * 4 + i) * 64 + ni * 16 + l15] =
                        f2b(S[mi][ni][i] * inv);
            }
        }
        __syncthreads();

        short8 bv[4][2];
        #pragma unroll
        for (int ni = 0; ni < 4; ni++)
            #pragma unroll
            for (int kt = 0; kt < 2; kt++)
                #pragma unroll
                for (int j = 0; j < 8; j++)
                    bv[ni][kt][j] = (short)vh[(size_t)(kt * 32 + quad * 8 + j) * kD
                                              + ni * 16 + l15];
        short8 pa[4][2];
        #pragma unroll
        for (int mi = 0; mi < 4; mi++)
            #pragma unroll
            for (int kt = 0; kt < 2; kt++)
                pa[mi][kt] = *(const short8*)&Pw[(mi * 16 + l15) * 64
                                                 + kt * 32 + quad * 8];
        f32x4 O[4][4];
        #pragma unroll
        for (int mi = 0; mi < 4; mi++)
            #pragma unroll
            for (int ni = 0; ni < 4; ni++)
                O[mi][ni] = (f32x4){0.f, 0.f, 0.f, 0.f};
        #pragma unroll
        for (int mi = 0; mi < 4; mi++)
            #pragma unroll
            for (int ni = 0; ni < 4; ni++) {
                O[mi][ni] = __builtin_amdgcn_mfma_f32_16x16x32_bf16(
                    pa[mi][0], bv[ni][0], O[mi][ni], 0, 0, 0);
                O[mi][ni] = __builtin_amdgcn_mfma_f32_16x16x32_bf16(
                    pa[mi][1], bv[ni][1], O[mi][ni], 0, 0, 0);
            }
        u16* qo = qbuf + base + h * 64;
        #pragma unroll
        for (int mi = 0; mi < 4; mi++)
            #pragma unroll
            for (int ni = 0; ni < 4; ni++)
                #pragma unroll
                for (int i = 0; i < 4; i++)
                    qo[(size_t)(mi * 16 + quad * 4 + i) * kD + ni * 16 + l15] =
                        f2b(O[mi][ni][i]);
        __syncthreads();
    }
}

// ---------------------------------------------------------------------------
// Row LayerNorm over D=512, bf16 in/out, in-place safe. 4 rows per block.
// ---------------------------------------------------------------------------
__global__ __launch_bounds__(256) void ln_kernel(
    const u16* __restrict__ x, const float* __restrict__ g,
    const float* __restrict__ bb, u16* __restrict__ y)
{
    size_t row = (size_t)blockIdx.x * 4 + (threadIdx.x >> 6);
    int lane = threadIdx.x & 63;
    float v[8];
    float s = 0.f;
    #pragma unroll
    for (int i = 0; i < 8; i++) {
        v[i] = b2f(x[row * kD + lane + i * 64]);
        s += v[i];
    }
    #pragma unroll
    for (int off = 32; off; off >>= 1) s += __shfl_xor(s, off);
    float mean = s * (1.f / kD);
    float sq = 0.f;
    #pragma unroll
    for (int i = 0; i < 8; i++) { float d = v[i] - mean; sq += d * d; }
    #pragma unroll
    for (int off = 32; off; off >>= 1) sq += __shfl_xor(sq, off);
    float inv = 1.f / sqrtf(sq * (1.f / kD) + 1e-5f);
    #pragma unroll
    for (int i = 0; i < 8; i++) {
        int d = lane + i * 64;
        y[row * kD + d] = f2b((v[i] - mean) * inv * g[d] + bb[d]);
    }
}

// ---------------------------------------------------------------------------
// BatchNorm pieces
// ---------------------------------------------------------------------------
__global__ void zero_kernel(float* __restrict__ p, int n)
{
    int i = blockIdx.x * blockDim.x + threadIdx.x;
    if (i < n) p[i] = 0.f;
}

__global__ __launch_bounds__(512) void bn_stats_kernel(
    const u16* __restrict__ tok, float* __restrict__ sums, float* __restrict__ sumsq)
{
    int d = threadIdx.x;
    float s = 0.f, sq = 0.f;
    int row0 = blockIdx.x * 256;
    for (int row = row0; row < row0 + 256; row++) {
        float v = b2f(tok[(size_t)row * kD + d]);
        s += v; sq += v * v;
    }
    atomicAdd(&sums[d], s);
    atomicAdd(&sumsq[d], sq);
}

__global__ __launch_bounds__(512) void bn_final_kernel(
    const float* __restrict__ sums, const float* __restrict__ sumsq,
    const float* __restrict__ g, const float* __restrict__ bb,
    float* __restrict__ scale, float* __restrict__ shift)
{
    int d = threadIdx.x;
    float mean = sums[d] / (float)kM;
    float var = sumsq[d] / (float)kM - mean * mean;
    float sc = g[d] / sqrtf(var + 1e-5f);
    scale[d] = sc;
    shift[d] = bb[d] - mean * sc;
}

// in-place BN on tok (bf16)
__global__ __launch_bounds__(256) void bn_apply_kernel(
    u16* __restrict__ tok, const float* __restrict__ scale,
    const float* __restrict__ shift)
{
    size_t i = (size_t)blockIdx.x * 256 + threadIdx.x;
    int d = (int)(i & 511);
    tok[i] = f2b(b2f(tok[i]) * scale[d] + shift[d]);
}

// out[(b*T+t)*C+c] = b_head[t]*stdev[r]+means[r]  (split-K partials add onto it)
__global__ __launch_bounds__(256) void head_init_kernel(
    float* __restrict__ out, const float* __restrict__ b_head,
    const float* __restrict__ stdev, const float* __restrict__ means)
{
    int i = blockIdx.x * 256 + threadIdx.x;
    int c = i & 31, t = (i >> 5) & 511, b = i >> 14;
    int r = b * 32 + c;
    out[i] = b_head[t] * stdev[r] + means[r];
}

// ---------------------------------------------------------------------------
// Launch
// ---------------------------------------------------------------------------
extern "C" void kernel_launch(void* const* d_in, const int* in_sizes, int n_in,
                              void* d_out, int out_size, void* d_ws, size_t ws_size,
                              hipStream_t stream)
{
    const float* x_enc  = (const float*)d_in[0];
    const float* W_val  = (const float*)d_in[1];
    const float* Wq     = (const float*)d_in[2];
    const float* bq     = (const float*)d_in[3];
    const float* Wk     = (const float*)d_in[4];
    const float* bk     = (const float*)d_in[5];
    const float* Wv     = (const float*)d_in[6];
    const float* bv     = (const float*)d_in[7];
    const float* Wo     = (const float*)d_in[8];
    const float* bo     = (const float*)d_in[9];
    const float* Wc1    = (const float*)d_in[10];
    const float* bc1    = (const float*)d_in[11];
    const float* Wc2    = (const float*)d_in[12];
    const float* bc2    = (const float*)d_in[13];
    const float* ln1_g  = (const float*)d_in[14];
    const float* ln1_b  = (const float*)d_in[15];
    const float* ln2_g  = (const float*)d_in[16];
    const float* ln2_b  = (const float*)d_in[17];
    const float* bn_g   = (const float*)d_in[18];
    const float* bn_b   = (const float*)d_in[19];
    const float* W_head = (const float*)d_in[20];
    const float* b_head = (const float*)d_in[21];
    float* out = (float*)d_out;

    // --- adaptive chunk size: largest CH with tok + 3 units + weights fitting
    const size_t tailBytes = (2 * kR + 4 * kD) * sizeof(float);
    const size_t headWb = (size_t)512 * 32768;   // W_head bf16 overlay elems
    int CH = 0; size_t unit = 0, region = 0;
    const int cands[4] = {1024, 512, 256, 128};
    for (int ci = 0; ci < 4; ci++) {
        size_t u = (size_t)cands[ci] * 64 * kD;
        size_t reg = 3 * u + kWbElems;
        if (reg < headWb) reg = headWb;
        size_t need = ((size_t)kM * kD + reg) * 2 + tailBytes;
        if (need <= ws_size) { CH = cands[ci]; unit = u; region = reg; break; }
    }
    if (CH == 0) {
        hipLaunchKernelGGL(fill_kernel, dim3((out_size + 255) / 256), dim3(256), 0,
                           stream, out, 1.0e6f, out_size);
        return;
    }
    const int nch = kR / CH;
    const int chRows = CH * 64;

    u16* tokb = (u16*)d_ws;
    u16* s0  = tokb + (size_t)kM * kD;
    u16* s1  = s0 + unit;
    u16* s2  = s1 + unit;
    u16* wbL = s2 + unit;
    u16* wbH = s0;
    u16* wQKV = wbL;                       // [1536][512]
    u16* wO   = wQKV + (size_t)1536 * 512; // [512][512]
    u16* wC1  = wO + (size_t)512 * 512;    // [2048][512]
    u16* wC2  = wC1 + (size_t)2048 * 512;  // [512][2048]
    float* tail = (float*)(s0 + region);
    float* means    = tail;
    float* stdevp   = means + kR;
    float* bn_sums  = stdevp + kR;
    float* bn_sumsq = bn_sums + kD;
    float* bn_scale = bn_sumsq + kD;
    float* bn_shift = bn_scale + kD;

    hipLaunchKernelGGL(instnorm_stats_kernel, dim3(kB), dim3(256), 0, stream,
                       x_enc, means, stdevp);
    hipLaunchKernelGGL(patch_embed_kernel, dim3(kM), dim3(256), 0, stream,
                       x_enc, W_val, means, stdevp, tokb);

    const dim3 blk(256);
    const dim3 tr8(8, 8, 1);
    const int mt = chRows / 128;   // M tiles per chunk

    for (int i = 0; i < kNL; i++) {
        const float* Wq_i = Wq + (size_t)i * kD * kD;
        const float* Wk_i = Wk + (size_t)i * kD * kD;
        const float* Wv_i = Wv + (size_t)i * kD * kD;
        const float* Wo_i = Wo + (size_t)i * kD * kD;
        const float* Wc1_i = Wc1 + (size_t)i * kD * kDFF;
        const float* Wc2_i = Wc2 + (size_t)i * kDFF * kD;
        const float* bq_i = bq + i * kD, *bk_i = bk + i * kD, *bv_i = bv + i * kD;

        hipLaunchKernelGGL(transpose_cvt_kernel, tr8, blk, 0, stream,
                           Wq_i, wQKV, kD, kD, 0, 0);
        hipLaunchKernelGGL(transpose_cvt_kernel, tr8, blk, 0, stream,
                           Wk_i, wQKV + (size_t)512 * 512, kD, kD, 0, 0);
        hipLaunchKernelGGL(transpose_cvt_kernel, tr8, blk, 0, stream,
                           Wv_i, wQKV + (size_t)1024 * 512, kD, kD, 0, 0);
        hipLaunchKernelGGL(transpose_cvt_kernel, tr8, blk, 0, stream,
                           Wo_i, wO, kD, kD, 0, 0);
        hipLaunchKernelGGL(transpose_cvt_kernel, dim3(8, 32, 1), blk, 0, stream,
                           Wc1_i, wC1, kDFF, kD, 0, 0);
        hipLaunchKernelGGL(transpose_cvt_kernel, dim3(32, 8, 1), blk, 0, stream,
                           Wc2_i, wC2, kD, kDFF, 0, 0);

        for (int ch = 0; ch < nch; ch++) {
            u16* tokc = tokb + (size_t)ch * chRows * kD;
            // fused QKV: N=1536, routed to s0/s1/s2
            hipLaunchKernelGGL(mfma_gemm<0>, dim3(12, mt, 1), blk, 0, stream,
                               tokc, wQKV, bq_i, bk_i, bv_i, s0, s1, s2,
                               nullptr, nullptr, kD, kD, kD, kD);
            hipLaunchKernelGGL(attn_mfma_kernel, dim3(CH), blk, 0, stream,
                               s0, s1, s2);
            // tok += attn_out @ Wo + bo
            hipLaunchKernelGGL(mfma_gemm<1>, dim3(4, mt, 1), blk, 0, stream,
                               s0, wO, bo + i * kD, nullptr, nullptr,
                               tokc, nullptr, nullptr, nullptr, nullptr,
                               kD, kD, kD, kD);
            // y = LN1(tok) -> s0
            hipLaunchKernelGGL(ln_kernel, dim3(chRows / 4), blk, 0, stream,
                               tokc, ln1_g + i * kD, ln1_b + i * kD, s0);
            // FFN in two DFF/2 halves; h lives in s1:s2 (2 units)
            for (int half = 0; half < 2; half++) {
                const u16* wc1h = wC1 + (size_t)half * 1024 * 512;
                const u16* wc2h = wC2 + (size_t)half * 1024;   // k-offset
                const float* bc1h = bc1 + (size_t)i * kDFF + half * 1024;
                hipLaunchKernelGGL(mfma_gemm<2>, dim3(8, mt, 1), blk, 0, stream,
                                   s0, wc1h, bc1h, nullptr, nullptr,
                                   s1, nullptr, nullptr, nullptr, nullptr,
                                   kD, kD, kD, 1024);
                hipLaunchKernelGGL(mfma_gemm<1>, dim3(4, mt, 1), blk, 0, stream,
                                   s1, wc2h, (half == 0) ? (bc2 + i * kD) : nullptr,
                                   nullptr, nullptr, tokc, nullptr, nullptr,
                                   nullptr, nullptr, 1024, 1024, kDFF, kD);
            }
            // tok = LN2(tok) in place
            hipLaunchKernelGGL(ln_kernel, dim3(chRows / 4), blk, 0, stream,
                               tokc, ln2_g + i * kD, ln2_b + i * kD, tokc);
        }
    }

    // BatchNorm (stats -> apply in place on tok)
    hipLaunchKernelGGL(zero_kernel, dim3(1), dim3(1024), 0, stream, bn_sums, 2 * kD);
    hipLaunchKernelGGL(bn_stats_kernel, dim3(kM / 256), dim3(512), 0, stream,
                       tokb, bn_sums, bn_sumsq);
    hipLaunchKernelGGL(bn_final_kernel, dim3(1), dim3(512), 0, stream,
                       bn_sums, bn_sumsq, bn_g, bn_b, bn_scale, bn_shift);
    hipLaunchKernelGGL(bn_apply_kernel, dim3((int)((size_t)kM * kD / 256)), blk, 0,
                       stream, tokb, bn_scale, bn_shift);

    // head weights: wbH[t][n*512+d] = W_head[(d*64+n)*512+t]  (k' = n*512+d)
    hipLaunchKernelGGL(transpose_cvt_kernel, dim3(8, 8, 64), blk, 0, stream,
                       W_head, wbH, 64 * 512, 32768, 512, 512);
    // out = b_head*stdev+mean, then split-K MFMA adds acc*stdev
    hipLaunchKernelGGL(head_init_kernel, dim3(out_size / 256), blk, 0, stream,
                       out, b_head, stdevp, means);
    // A = tok viewed as [1024][32768] (k'=n*512+d is the flat tok order)
    hipLaunchKernelGGL(mfma_gemm<3>, dim3(4, 8, 8), blk, 0, stream,
                       tokb, wbH, nullptr, nullptr, nullptr,
                       nullptr, nullptr, nullptr, out, stdevp,
                       4096, 32768, 32768, kT);
}